// Round 10
// baseline (1417.499 us; speedup 1.0000x reference)
//
#include <hip/hip_runtime.h>
#include <math.h>

constexpr int B_ = 2, C_ = 32, NS = 32, NZ = 96, NX = 96;
constexpr int KS = 16, KZ = 24, KX = 12;          // kept mode counts (s, z, x)
constexpr int NPTS = B_ * NS * NZ * NX;           // 589824
constexpr int CHS  = NS * NZ * NX;                // 294912 (per-channel stride)
constexpr size_t HSIZE = (size_t)B_ * C_ * CHS;   // 18,874,368 floats

constexpr size_t FX_C  = (size_t)B_ * C_ * NS * KX * NZ;  // 2,359,296 cplx (gz)
constexpr size_t FZX_C = (size_t)B_ * C_ * KZ * KX * NS;  //   589,824 cplx (fzx)
constexpr size_t FS_C  = (size_t)B_ * C_ * KS * KZ * KX;  //   294,912 cplx

// workspace offsets (floats). gz overlays FX.
constexpr size_t OFF_HA   = 0;
constexpr size_t OFF_HB   = OFF_HA + HSIZE;
constexpr size_t OFF_FX   = OFF_HB + HSIZE;
constexpr size_t OFF_FZX  = OFF_FX + 2 * FX_C;
constexpr size_t OFF_FS   = OFF_FZX + 2 * FZX_C;
constexpr size_t OFF_G    = OFF_FS + 2 * FS_C;
constexpr size_t OFF_ST   = OFF_G + 2 * FS_C;     // (legacy, unused)
constexpr size_t OFF_SC   = OFF_ST + 256;         // 4 layers x (scale[32], shift[32])
constexpr size_t OFF_TWXF = OFF_SC + 256;         // [x=96][k=12] cplx, e^{-i}
constexpr size_t OFF_TWZF = OFF_TWXF + 2 * 96 * 12;   // [z=96][k=24]
constexpr size_t OFF_TWSF = OFF_TWZF + 2 * 96 * 24;   // [s=32][k=16], includes 1/294912
constexpr size_t OFF_TWSI = OFF_TWSF + 2 * 32 * 16;   // [k=16][s=32] cplx, e^{+i}
constexpr size_t OFF_TWZI = OFF_TWSI + 2 * 16 * 32;   // [k=24][z=96]
constexpr size_t OFF_TWXI = OFF_TWZI + 2 * 24 * 96;   // [k=12][x=96]
// BN-stat PARTIALS: 4 layers x 64 slots x (sum[32],sumsq[32]) = 16384 floats.
// Hashed by (blockIdx & 63) (r6 post-mortem: single-copy same-address atomics
// from 6144 blocks serialized in L2 -> 331us; hashing fixed it to 90us, r7).
constexpr size_t OFF_STP  = OFF_TWXI + 2 * 12 * 96;

__global__ void k_init_tw(float* ws) {
  const double TWO_PI = 6.283185307179586476925286766559;
  int t = threadIdx.x;
  float2* twxf = (float2*)(ws + OFF_TWXF);
  for (int i = t; i < 96 * 12; i += 256) {
    int x = i / 12, k = i % 12;
    double a = -TWO_PI * (double)((k * x) % 96) / 96.0;
    twxf[i] = make_float2((float)cos(a), (float)sin(a));
  }
  float2* twzf = (float2*)(ws + OFF_TWZF);
  for (int i = t; i < 96 * 24; i += 256) {
    int z = i / 24, k = i % 24;
    double a = -TWO_PI * (double)((k * z) % 96) / 96.0;
    twzf[i] = make_float2((float)cos(a), (float)sin(a));
  }
  float2* twsf = (float2*)(ws + OFF_TWSF);
  const double SC = 1.0 / (double)(NS * NZ * NX);  // fftn norm='forward'
  for (int i = t; i < 32 * 16; i += 256) {
    int s = i / 16, k = i % 16;
    int f = (k < 8) ? k : k + 16;                  // s-modes 0..7, 24..31
    double a = -TWO_PI * (double)((f * s) % 32) / 32.0;
    twsf[i] = make_float2((float)(cos(a) * SC), (float)(sin(a) * SC));
  }
  float2* twsi = (float2*)(ws + OFF_TWSI);
  for (int i = t; i < 16 * 32; i += 256) {
    int k = i / 32, s = i % 32;
    int f = (k < 8) ? k : k + 16;
    double a = TWO_PI * (double)((f * s) % 32) / 32.0;
    twsi[i] = make_float2((float)cos(a), (float)sin(a));
  }
  float2* twzi = (float2*)(ws + OFF_TWZI);
  for (int i = t; i < 24 * 96; i += 256) {
    int k = i / 96, z = i % 96;
    int f = (k < 12) ? k : k + 72;                 // z-modes 0..11, 84..95
    double a = TWO_PI * (double)((f * z) % 96) / 96.0;
    twzi[i] = make_float2((float)cos(a), (float)sin(a));
  }
  float2* twxi = (float2*)(ws + OFF_TWXI);
  for (int i = t; i < 12 * 96; i += 256) {
    int k = i / 96, x = i % 96;
    double a = TWO_PI * (double)((k * x) % 96) / 96.0;
    twxi[i] = make_float2((float)cos(a), (float)sin(a));
  }
}

__global__ void k_zero_stats(float* stp) {
  stp[blockIdx.x * 256 + threadIdx.x] = 0.f;   // 64 blocks x 256 = 16384 floats
}

// Fused dftx+dftz. block = (b,c,s). Stage BN(h) plane in LDS (coalesced, +97
// pad), dftx with 6 complex reg-accumulators per thread + SCALAR twiddles
// (half = t>>7 is wave-uniform), dftz with dual accumulators.
// Layer 0 (use_bn==0): h is never materialized -- compute the plane from the
// xin (b,s) slab on the fly (h = x0*w0[c]+x1*w1[c]+b[c]; xin is 4.7MB total,
// L2-resident across the 32 channel-blocks that re-read each slab).
// Output fzx[bcs][kz*12+kx] contiguous per block.
__global__ __launch_bounds__(256) void k_fwd(const float* __restrict__ h, const float* __restrict__ xin,
                      const float* __restrict__ fc0w, const float* __restrict__ fc0b,
                      float2* __restrict__ fzx,
                      const float2* __restrict__ twxf, const float2* __restrict__ twzf,
                      const float* __restrict__ sc, int use_bn) {
  __shared__ float  sh_h[96 * 97];     // 37.2 KB
  __shared__ float2 sh_fx[96 * 12];    // 9 KB  [z][kx]
  int t = threadIdx.x;
  int bcs = blockIdx.x;               // 2048 = 64 bc * 32 s
  int s = bcs & 31;
  int bc = bcs >> 5;
  int c = bc & 31;
  int b = bc >> 5;
  if (use_bn) {
    float scale = sc[c];
    float shift = sc[32 + c];
    const float* hp = h + (size_t)bc * CHS + (size_t)s * (NZ * NX);
    for (int i = t; i < NZ * NX; i += 256) {
      float v = hp[i];                   // coalesced row-major
      v = v * scale + shift;
      v = v >= 0.f ? v : v * 0.1f;
      sh_h[(i / 96) * 97 + (i % 96)] = v;
    }
  } else {
    // layer 0: expand fc0 on the fly from xin (no BN, no leaky)
    float w0 = fc0w[c], w1v = fc0w[C_ + c], bb = fc0b[c];
    const float2* xp = (const float2*)xin + ((size_t)b * NS + s) * (NZ * NX);
    for (int i = t; i < NZ * NX; i += 256) {
      float2 xv = xp[i];                 // coalesced, L2-hot
      sh_h[(i / 96) * 97 + (i % 96)] = xv.x * w0 + xv.y * w1v + bb;
    }
  }
  __syncthreads();
  // dftx: waves 0-1 -> kx 0..5, waves 2-3 -> kx 6..11; z = t&127 (<96 active)
  {
    int half = __builtin_amdgcn_readfirstlane(t >> 7);   // wave-uniform
    int z = t & 127;
    if (z < 96) {
      float ar[6], ai[6];
      #pragma unroll
      for (int j = 0; j < 6; ++j) { ar[j] = 0.f; ai[j] = 0.f; }
      const float2* twx = twxf + half * 6;
      const float* row = sh_h + z * 97;
      for (int x = 0; x < 96; ++x) {
        float v = row[x];              // 1 ds_read per 12 FMAs
        #pragma unroll
        for (int j = 0; j < 6; ++j) {
          float2 w = twx[x * 12 + j];  // wave-uniform -> s_load (K$-hot)
          ar[j] += v * w.x; ai[j] += v * w.y;
        }
      }
      #pragma unroll
      for (int j = 0; j < 6; ++j)
        sh_fx[z * 12 + half * 6 + j] = make_float2(ar[j], ai[j]);
    }
  }
  __syncthreads();
  // dftz: item = (kz,kx), 288 items; dual accumulators, tw L1-hot vector loads
  float2* outp = fzx + (size_t)bcs * 288;
  for (int it = t; it < 288; it += 256) {
    int kx = it % 12, kz = it / 12;
    float ar0 = 0.f, ai0 = 0.f, ar1 = 0.f, ai1 = 0.f;
    for (int z = 0; z < 96; z += 2) {
      float2 v0 = sh_fx[z * 12 + kx];
      float2 w0 = twzf[z * 24 + kz];
      float2 v1 = sh_fx[(z + 1) * 12 + kx];
      float2 w1 = twzf[(z + 1) * 24 + kz];
      ar0 += v0.x * w0.x - v0.y * w0.y;
      ai0 += v0.x * w0.y + v0.y * w0.x;
      ar1 += v1.x * w1.x - v1.y * w1.y;
      ai1 += v1.x * w1.y + v1.y * w1.x;
    }
    outp[it] = make_float2(ar0 + ar1, ai0 + ai1);   // coalesced
  }
}

// Fs[bc][ks*288+kzkx] = sum_s Fzx[bc][s][kzkx] * tw; thread per output.
__global__ __launch_bounds__(256) void k_dfts(const float2* __restrict__ fzx, float2* __restrict__ fs,
                       const float2* __restrict__ tw) {
  int tid = blockIdx.x * 256 + threadIdx.x;   // 294,912
  int kzkx = tid % 288;
  int ks = (tid / 288) & 15;
  int bc = tid / 4608;
  const float2* src = fzx + (size_t)bc * (32 * 288) + kzkx;
  float ar = 0.f, ai = 0.f;
  #pragma unroll 8
  for (int s = 0; s < 32; ++s) {
    float2 v = src[s * 288];
    float2 w = tw[s * 16 + ks];
    ar += v.x * w.x - v.y * w.y;
    ai += v.x * w.y + v.y * w.x;
  }
  fs[(size_t)bc * 4608 + ks * 288 + kzkx] = make_float2(ar, ai);
}

// G[b][o][fidx] = sum_i Fs[b][i][fidx] * w[l,q,i,o,mode]; lanes = consecutive modes
__global__ __launch_bounds__(256) void k_mix(const float2* __restrict__ fs, const float* __restrict__ spec,
                      int l, float2* __restrict__ g) {
  int tid = blockIdx.x * 256 + threadIdx.x;   // 147,456 = 4q * 32o * 1152m
  int m = tid % 1152;
  int o = (tid / 1152) & 31;
  int q = tid / 36864;
  int m1 = m / 144, r = m - m1 * 144, m2 = r / 12, m3 = r - m2 * 12;
  int ks = m1 + (q & 1) * 8;
  int kz = m2 + ((q >> 1) & 1) * 12;
  int fidx = (ks * KZ + kz) * KX + m3;
  const float2* w2 = (const float2*)spec;
  size_t widx = ((size_t)(l * 4 + q) * 1024 + o) * 1152 + m;   // + i*36864 per i
  const float2* f0 = fs + fidx;                                 // + i*4608 per i
  const float2* f1 = fs + (size_t)C_ * 4608 + fidx;
  float a0r = 0.f, a0i = 0.f, a1r = 0.f, a1i = 0.f;
  #pragma unroll 4
  for (int i = 0; i < C_; ++i) {
    float2 w = w2[widx];  widx += 36864;
    float2 v0 = f0[(size_t)i * 4608];
    float2 v1 = f1[(size_t)i * 4608];
    a0r += v0.x * w.x - v0.y * w.y;  a0i += v0.x * w.y + v0.y * w.x;
    a1r += v1.x * w.x - v1.y * w.y;  a1i += v1.x * w.y + v1.y * w.x;
  }
  g[(size_t)o * 4608 + fidx] = make_float2(a0r, a0i);
  g[(size_t)(C_ + o) * 4608 + fidx] = make_float2(a1r, a1i);
}

// Fused idfts+idftz. block = (bo, s): stage g[bo] (36.9 KB) in LDS, compute
// gs slice [288] in LDS (16-term s-inverse, twiddles via s_load since s is
// block-uniform), then gz row [z=96][kx=12] (24-term z-inverse, twzi L1-hot).
// Eliminates the gs global round-trip and one launch per layer (r6 ledger:
// ~-20us/layer vs separate idfts+idftz). LDS 39.2 KB -> 4 blocks/CU.
__global__ __launch_bounds__(256) void k_idft_sz(const float2* __restrict__ g, float2* __restrict__ gz,
                        const float2* __restrict__ twsi, const float2* __restrict__ twzi) {
  __shared__ float2 sh_g[4608];    // 36.9 KB, this bo's full G
  __shared__ float2 sh_gs[288];    // 2.3 KB, gs slice for this s
  int t = threadIdx.x;
  int bo = blockIdx.x >> 5;
  int s  = blockIdx.x & 31;
  const float2* gsrc = g + (size_t)bo * 4608;
  for (int i = t; i < 4608; i += 256) sh_g[i] = gsrc[i];   // coalesced, L2-hot
  __syncthreads();
  // gs[kzkx] = sum_ks sh_g[ks*288+kzkx] * twsi[ks*32+s]  (twsi: s_load)
  for (int it = t; it < 288; it += 256) {
    float ar = 0.f, ai = 0.f;
    #pragma unroll
    for (int ks = 0; ks < 16; ++ks) {
      float2 v = sh_g[ks * 288 + it];
      float2 w = twsi[ks * 32 + s];
      ar += v.x * w.x - v.y * w.y;
      ai += v.x * w.y + v.y * w.x;
    }
    sh_gs[it] = make_float2(ar, ai);
  }
  __syncthreads();
  // gz[z][kx] = sum_kz sh_gs[kz*12+kx] * twzi[kz*96+z]
  float2* outp = gz + (size_t)(bo * 32 + s) * 1152;
  for (int it = t; it < 1152; it += 256) {
    int kx = it % 12, z = it / 12;
    float ar = 0.f, ai = 0.f;
    #pragma unroll 8
    for (int kz = 0; kz < 24; ++kz) {
      float2 v = sh_gs[kz * 12 + kx];
      float2 w = twzi[kz * 96 + z];
      ar += v.x * w.x - v.y * w.y;
      ai += v.x * w.y + v.y * w.x;
    }
    outp[it] = make_float2(ar, ai);    // coalesced
  }
}

// a[b][o][s][z][x] = Re(sum_kx Gz e^{+..}) + sum_i ww[o][i] h_bn[b][i][s][z][x] + wb[o]
// r7 256-thread version (r8's z-pair variant REGRESSED 90->106us -- reverted).
// gz staged in LDS; ww/wb on the scalar path. Layer 0 (use_bn==0): h never
// materialized -- expand fc0 from the xin row. BN-stats fused with
// slot-hashed atomics (r6/r7).
__global__ __launch_bounds__(256) void k_idftx_fuse(const float2* __restrict__ gz, const float* __restrict__ hsrc,
                             const float* __restrict__ xin, const float* __restrict__ fc0w,
                             const float* __restrict__ fc0b,
                             const float* __restrict__ ww, const float* __restrict__ wb,
                             const float2* __restrict__ twxi, const float* __restrict__ sc,
                             int use_bn, float* __restrict__ adst, float* __restrict__ stp) {
  __shared__ float  sh_h[C_ * NX];    // 12 KB, post-BN+leaky; later [o][x] scratch
  __shared__ float2 sh_g[C_ * KX];    // 3 KB, this (b,s,z)'s 32x12 gz fragments
  int blk = blockIdx.x;               // z fastest
  int z = blk % NZ, s = (blk / NZ) % NS, b = blk / (NZ * NS);
  int t = threadIdx.x;
  size_t rowbase = ((size_t)b * C_) * CHS + (size_t)s * (NZ * NX) + (size_t)z * NX;
  if (use_bn) {
    for (int i = t; i < C_ * NX; i += 256) {
      int c = i / NX, x = i % NX;
      float v = hsrc[rowbase + (size_t)c * CHS + x];
      v = v * sc[c] + sc[32 + c];
      sh_h[i] = v >= 0.f ? v : v * 0.1f;
    }
  } else {
    // layer 0: expand fc0 from xin row (no BN, no leaky)
    const float2* xp = (const float2*)xin + (((size_t)b * NS + s) * NZ + z) * NX;
    for (int i = t; i < C_ * NX; i += 256) {
      int c = i / NX, x = i % NX;
      float2 xv = xp[x];               // L1-hot (row re-read across c)
      sh_h[i] = xv.x * fc0w[c] + xv.y * fc0w[C_ + c] + fc0b[c];
    }
  }
  // stage gz: 384 float2; thread i -> (o = i/12, kx = i%12); 96B contiguous runs
  for (int i = t; i < C_ * KX; i += 256) {
    int o = i / KX, kx = i % KX;
    sh_g[i] = gz[(((size_t)(b * C_ + o) * NS + s) * NZ + z) * KX + kx];
  }
  __syncthreads();
  int x = t & 127;
  int og = __builtin_amdgcn_readfirstlane(t >> 7);   // wave-uniform
  float acc[16];
  if (x < NX) {
    float2 tw[KX];
    #pragma unroll
    for (int k = 0; k < KX; ++k) tw[k] = twxi[k * NX + x];
    #pragma unroll
    for (int j = 0; j < 16; ++j) {
      int o = og * 16 + j;
      float a = wb[o];                                  // s_load
      const float2* gp = sh_g + o * KX;                 // LDS broadcast (free)
      #pragma unroll
      for (int k = 0; k < KX; ++k) {
        float2 gv = gp[k];
        a += gv.x * tw[k].x - gv.y * tw[k].y;
      }
      acc[j] = a;
    }
    for (int i = 0; i < C_; ++i) {
      float val = sh_h[i * NX + x];
      #pragma unroll
      for (int j = 0; j < 16; ++j) acc[j] += ww[(og * 16 + j) * C_ + i] * val;  // s_load
    }
    #pragma unroll
    for (int j = 0; j < 16; ++j)
      adst[rowbase + (size_t)(og * 16 + j) * CHS + x] = acc[j];
  }
  // ---- fused BN stats: reduce raw acc over this block's 96 x per channel ----
  __syncthreads();                    // everyone done reading sh_h
  if (x < NX) {
    #pragma unroll
    for (int j = 0; j < 16; ++j) sh_h[(og * 16 + j) * NX + x] = acc[j];
  }
  __syncthreads();
  {
    int o = t >> 3, ch = t & 7;       // 32 channels x 8 chunks of 12
    const float* row = sh_h + o * NX + ch * 12;
    float s1 = 0.f, s2 = 0.f;
    #pragma unroll
    for (int k = 0; k < 12; ++k) { float v = row[k]; s1 += v; s2 += v * v; }
    s1 += __shfl_down(s1, 4);  s2 += __shfl_down(s2, 4);
    s1 += __shfl_down(s1, 2);  s2 += __shfl_down(s2, 2);
    s1 += __shfl_down(s1, 1);  s2 += __shfl_down(s2, 1);
    if (ch == 0) {
      float* slot = stp + (size_t)(blk & 63) * 64;     // hashed partial copy
      atomicAdd(&slot[o], s1);
      atomicAdd(&slot[32 + o], s2);
    }
  }
}

// reduce 64 partial slots -> (scale, shift) for this layer
__global__ void k_bnfinal(const float* __restrict__ stp, const float* __restrict__ g,
                          const float* __restrict__ bb, float* __restrict__ sc) {
  __shared__ float tot[64];
  int t = threadIdx.x;                // 64 threads
  float s = 0.f;
  for (int slot = 0; slot < 64; ++slot) s += stp[slot * 64 + t];
  tot[t] = s;
  __syncthreads();
  if (t < 32) {
    const float N = (float)NPTS;
    float mean = tot[t] / N;
    float var = tot[32 + t] / N - mean * mean;
    float inv = rsqrtf(var + 1e-5f);
    float scale = inv * g[t];
    sc[t] = scale;
    sc[32 + t] = bb[t] - mean * scale;
  }
}

// MLP, LDS-activation + scalar-weight design, 512-thread blocks (8 waves).
// r10: all LDS activation reads vectorized to float2 (ds_read_b64).
// Strides A:65->66, Bf:129->130 keep rows 8B-aligned for even k (66p+k even);
// bank index (2p+k)%32 -> only lanes p,p+16 alias = 2-way (free, m136).
// Halves LDS issue count in every fc phase (r9: VALU 64% with ~340 scalar
// ds_reads/point on the critical path). LDS 51.25KB -> still 3 blocks/CU.
__global__ __launch_bounds__(512, 6) void k_mlp(
    const float* __restrict__ h, const float* __restrict__ xin,
    const float* __restrict__ sc, int blk0,
    const float* __restrict__ w1, const float* __restrict__ b1,
    const float* __restrict__ w2, const float* __restrict__ b2,
    const float* __restrict__ w3, const float* __restrict__ b3,
    const float* __restrict__ w4, const float* __restrict__ b4,
    const float* __restrict__ w5, const float* __restrict__ b5,
    const float* __restrict__ w7, const float* __restrict__ b7,
    float* __restrict__ out) {
  __shared__ float A[64 * 66];    // 16.9 KB (32/64-wide activations)
  __shared__ float Bf[64 * 130];  // 33.3 KB (128/32-wide activations)
  __shared__ float P[64 * 9];     // 2.3 KB (fc7 per-wave partials)
  int t = threadIdx.x;
  int p = t & 63;                                      // point within block
  int q = __builtin_amdgcn_readfirstlane(t >> 6);      // wave id 0..7, uniform
  int pt0 = (blockIdx.x + blk0) * 64;

  // phase 0: A[p][c] = leaky(BN3(h)); lanes -> consecutive points (coalesced)
  for (int i = t; i < 64 * 32; i += 512) {
    int c = i >> 6, pp = i & 63;
    int pt = pt0 + pp;
    size_t base = (size_t)(pt / CHS) * C_ * CHS + (pt % CHS);
    float v = h[base + (size_t)c * CHS];
    v = v * sc[c] + sc[32 + c];                        // sc via s_load
    A[pp * 66 + c] = v >= 0.f ? v : 0.1f * v;
  }
  __syncthreads();

  // phase 1: fc1 (32->128): A -> Bf, 16 outputs/thread (m0 = q*16)
  {
    const int m0 = q * 16;
    float acc[16];
    #pragma unroll
    for (int j = 0; j < 16; ++j) acc[j] = b1[m0 + j];
    const float2* arow2 = (const float2*)(A + p * 66);
    #pragma unroll 4
    for (int k2 = 0; k2 < 16; ++k2) {
      float2 a2 = arow2[k2];                           // ds_read_b64
      const float* wrA = w1 + (2 * k2) * 128 + m0;     // uniform -> s_load
      const float* wrB = w1 + (2 * k2 + 1) * 128 + m0;
      #pragma unroll
      for (int j = 0; j < 16; ++j) acc[j] += a2.x * wrA[j];
      #pragma unroll
      for (int j = 0; j < 16; ++j) acc[j] += a2.y * wrB[j];
    }
    float* brow = Bf + p * 130 + m0;
    #pragma unroll
    for (int j = 0; j < 16; ++j) {
      float v = acc[j];
      brow[j] = v >= 0.f ? v : 0.1f * v;
    }
  }
  __syncthreads();

  // phase 2: fc2 (128->64): Bf -> A, 8 outputs/thread (m0 = q*8)
  {
    const int m0 = q * 8;
    float acc[8];
    #pragma unroll
    for (int j = 0; j < 8; ++j) acc[j] = b2[m0 + j];
    const float2* brow2 = (const float2*)(Bf + p * 130);
    #pragma unroll 4
    for (int k2 = 0; k2 < 64; ++k2) {
      float2 a2 = brow2[k2];                           // ds_read_b64
      const float* wrA = w2 + (2 * k2) * 64 + m0;
      const float* wrB = w2 + (2 * k2 + 1) * 64 + m0;
      #pragma unroll
      for (int j = 0; j < 8; ++j) acc[j] += a2.x * wrA[j];
      #pragma unroll
      for (int j = 0; j < 8; ++j) acc[j] += a2.y * wrB[j];
    }
    float* arow = A + p * 66 + m0;
    #pragma unroll
    for (int j = 0; j < 8; ++j) {
      float v = acc[j];
      arow[j] = v >= 0.f ? v : 0.1f * v;
    }
  }
  __syncthreads();

  // phase 3: fc3 (64->32): A -> Bf (low cols), 4 outputs/thread (m0 = q*4)
  {
    const int m0 = q * 4;
    float acc[4];
    #pragma unroll
    for (int j = 0; j < 4; ++j) acc[j] = b3[m0 + j];
    const float2* arow2 = (const float2*)(A + p * 66);
    #pragma unroll 4
    for (int k2 = 0; k2 < 32; ++k2) {
      float2 a2 = arow2[k2];                           // ds_read_b64
      const float* wrA = w3 + (2 * k2) * 32 + m0;
      const float* wrB = w3 + (2 * k2 + 1) * 32 + m0;
      #pragma unroll
      for (int j = 0; j < 4; ++j) acc[j] += a2.x * wrA[j];
      #pragma unroll
      for (int j = 0; j < 4; ++j) acc[j] += a2.y * wrB[j];
    }
    float* brow = Bf + p * 130 + m0;
    #pragma unroll
    for (int j = 0; j < 4; ++j) {
      float v = acc[j];
      brow[j] = v >= 0.f ? v : 0.1f * v;
    }
  }
  __syncthreads();

  // phase 4: fc4 (32->64): Bf -> A, 8 outputs/thread (m0 = q*8)
  {
    const int m0 = q * 8;
    float acc[8];
    #pragma unroll
    for (int j = 0; j < 8; ++j) acc[j] = b4[m0 + j];
    const float2* brow2 = (const float2*)(Bf + p * 130);
    #pragma unroll 4
    for (int k2 = 0; k2 < 16; ++k2) {
      float2 a2 = brow2[k2];                           // ds_read_b64
      const float* wrA = w4 + (2 * k2) * 64 + m0;
      const float* wrB = w4 + (2 * k2 + 1) * 64 + m0;
      #pragma unroll
      for (int j = 0; j < 8; ++j) acc[j] += a2.x * wrA[j];
      #pragma unroll
      for (int j = 0; j < 8; ++j) acc[j] += a2.y * wrB[j];
    }
    float* arow = A + p * 66 + m0;
    #pragma unroll
    for (int j = 0; j < 8; ++j) {
      float v = acc[j];
      arow[j] = v >= 0.f ? v : 0.1f * v;
    }
  }
  __syncthreads();

  // phase 5: fc5 (64->128) fused with fc7 (128->1): per-wave partial dot
  {
    const int m0 = q * 16;
    float acc[16];
    #pragma unroll
    for (int j = 0; j < 16; ++j) acc[j] = b5[m0 + j];
    const float2* arow2 = (const float2*)(A + p * 66);
    #pragma unroll 4
    for (int k2 = 0; k2 < 32; ++k2) {
      float2 a2 = arow2[k2];                           // ds_read_b64
      const float* wrA = w5 + (2 * k2) * 128 + m0;
      const float* wrB = w5 + (2 * k2 + 1) * 128 + m0;
      #pragma unroll
      for (int j = 0; j < 16; ++j) acc[j] += a2.x * wrA[j];
      #pragma unroll
      for (int j = 0; j < 16; ++j) acc[j] += a2.y * wrB[j];
    }
    float partial = 0.f;
    #pragma unroll
    for (int j = 0; j < 16; ++j) {
      float v = acc[j];
      v = v >= 0.f ? v : 0.1f * v;                     // leaky(fc5)
      partial += v * w7[m0 + j];                       // s_load
    }
    P[p * 9 + q] = partial;
  }
  __syncthreads();

  // phase 6: wave 0 reduces the 8 partials, applies mask, stores
  if (q == 0) {
    int pt = pt0 + p;
    float acc = b7[0];
    #pragma unroll
    for (int j = 0; j < 8; ++j) acc += P[p * 9 + j];
    float T0 = xin[2 * pt + 1];
    float mask = (T0 < 0.01f) ? T0 : 1.0f;
    int z = (pt / NX) % NZ;
    if (z < 2) mask = 0.f;
    out[pt] = acc * mask;
  }
}

__global__ void k_loss(const float* __restrict__ tau, const float* __restrict__ xin,
                       const float* __restrict__ y, float* __restrict__ loss) {
  int pt = blockIdx.x * 256 + threadIdx.x;
  int x = pt % NX, z = (pt / NX) % NZ;
  float tpx = (x < NX - 1) ? tau[pt + 1] : 0.f;
  float tmx = (x > 0) ? tau[pt - 1] : 0.f;
  float tpz = (z < NZ - 1) ? tau[pt + NX] : 0.f;
  float tmz = (z > 0) ? tau[pt - NX] : 0.f;
  float Tpx = (x < NX - 1) ? xin[2 * (pt + 1) + 1] : 0.f;
  float Tmx = (x > 0) ? xin[2 * (pt - 1) + 1] : 0.f;
  float Tpz = (z < NZ - 1) ? xin[2 * (pt + NX) + 1] : 0.f;
  float Tmz = (z > 0) ? xin[2 * (pt - NX) + 1] : 0.f;
  float dx = (tpx - tmx) * 50.f + (Tpx - Tmx) * 50.f;
  float dz = (tpz - tmz) * 50.f + (Tpz - Tmz) * 50.f;
  loss[pt] = dx * dx + dz * dz - y[pt];
}

extern "C" void kernel_launch(void* const* d_in, const int* in_sizes, int n_in,
                              void* d_out, int out_size, void* d_ws, size_t ws_size,
                              hipStream_t stream) {
  (void)in_sizes; (void)n_in; (void)out_size; (void)ws_size;
  const float* xin    = (const float*)d_in[0];
  const float* y      = (const float*)d_in[1];
  const float* fc0_w  = (const float*)d_in[2];
  const float* fc0_b  = (const float*)d_in[3];
  const float* spec_w = (const float*)d_in[4];
  const float* w_w    = (const float*)d_in[5];
  const float* w_b    = (const float*)d_in[6];
  const float* bn_g   = (const float*)d_in[7];
  const float* bn_b   = (const float*)d_in[8];
  const float* fc1_w  = (const float*)d_in[9];
  const float* fc1_b  = (const float*)d_in[10];
  const float* fc2_w  = (const float*)d_in[11];
  const float* fc2_b  = (const float*)d_in[12];
  const float* fc3_w  = (const float*)d_in[13];
  const float* fc3_b  = (const float*)d_in[14];
  const float* fc4_w  = (const float*)d_in[15];
  const float* fc4_b  = (const float*)d_in[16];
  const float* fc5_w  = (const float*)d_in[17];
  const float* fc5_b  = (const float*)d_in[18];
  const float* fc7_w  = (const float*)d_in[19];
  const float* fc7_b  = (const float*)d_in[20];
  float* ws  = (float*)d_ws;
  float* out = (float*)d_out;

  k_init_tw<<<1, 256, 0, stream>>>(ws);
  k_zero_stats<<<64, 256, 0, stream>>>(ws + OFF_STP);
  // NOTE: no k_fc0 -- layer 0 expands fc0 on the fly in k_fwd/k_idftx_fuse.

  float* hsrc = ws + OFF_HA;   // unwritten for l=0; layer-0 kernels don't read it
  float* hdst = ws + OFF_HB;
  for (int l = 0; l < 4; ++l) {
    const float* sc_prev = ws + OFF_SC + (size_t)(l - 1) * 64;  // only read if l>0
    int use_bn = (l > 0) ? 1 : 0;
    float* stp_l = ws + OFF_STP + (size_t)l * 4096;
    k_fwd<<<B_ * C_ * NS, 256, 0, stream>>>(hsrc, xin, fc0_w, fc0_b,
                                            (float2*)(ws + OFF_FZX),
                                            (const float2*)(ws + OFF_TWXF),
                                            (const float2*)(ws + OFF_TWZF), sc_prev, use_bn);
    k_dfts<<<1152, 256, 0, stream>>>((const float2*)(ws + OFF_FZX), (float2*)(ws + OFF_FS),
                                     (const float2*)(ws + OFF_TWSF));
    k_mix<<<576, 256, 0, stream>>>((const float2*)(ws + OFF_FS), spec_w, l,
                                   (float2*)(ws + OFF_G));
    k_idft_sz<<<64 * 32, 256, 0, stream>>>((const float2*)(ws + OFF_G), (float2*)(ws + OFF_FX),
                                           (const float2*)(ws + OFF_TWSI),
                                           (const float2*)(ws + OFF_TWZI));
    k_idftx_fuse<<<B_ * NS * NZ, 256, 0, stream>>>((const float2*)(ws + OFF_FX), hsrc,
                                                   xin, fc0_w, fc0_b,
                                                   w_w + (size_t)l * C_ * C_, w_b + (size_t)l * C_,
                                                   (const float2*)(ws + OFF_TWXI), sc_prev,
                                                   use_bn, hdst, stp_l);
    k_bnfinal<<<1, 64, 0, stream>>>(stp_l, bn_g + (size_t)l * C_,
                                    bn_b + (size_t)l * C_, ws + OFF_SC + (size_t)l * 64);
    float* tmp = hsrc; hsrc = hdst; hdst = tmp;
  }

  // 8 sub-launches of 1152 blocks: keeps per-dispatch dur small so spectral
  // kernels stay visible in the rocprof top-5 (diagnostic; ~15us cost)
  for (int part = 0; part < 8; ++part) {
    k_mlp<<<1152, 512, 0, stream>>>(hsrc, xin, ws + OFF_SC + 192, part * 1152,
                                    fc1_w, fc1_b, fc2_w, fc2_b, fc3_w, fc3_b,
                                    fc4_w, fc4_b, fc5_w, fc5_b, fc7_w, fc7_b, out);
  }
  k_loss<<<NPTS / 256, 256, 0, stream>>>(out, xin, y, out + NPTS);
}

// Round 11
// 1379.705 us; speedup vs baseline: 1.0274x; 1.0274x over previous
//
#include <hip/hip_runtime.h>
#include <math.h>

constexpr int B_ = 2, C_ = 32, NS = 32, NZ = 96, NX = 96;
constexpr int KS = 16, KZ = 24, KX = 12;          // kept mode counts (s, z, x)
constexpr int NPTS = B_ * NS * NZ * NX;           // 589824
constexpr int CHS  = NS * NZ * NX;                // 294912 (per-channel stride)
constexpr size_t HSIZE = (size_t)B_ * C_ * CHS;   // 18,874,368 floats

constexpr size_t FX_C  = (size_t)B_ * C_ * NS * KX * NZ;  // 2,359,296 cplx (gz)
constexpr size_t FZX_C = (size_t)B_ * C_ * KZ * KX * NS;  //   589,824 cplx (fzx)
constexpr size_t FS_C  = (size_t)B_ * C_ * KS * KZ * KX;  //   294,912 cplx

// workspace offsets (floats). gz overlays FX.
constexpr size_t OFF_HA   = 0;
constexpr size_t OFF_HB   = OFF_HA + HSIZE;
constexpr size_t OFF_FX   = OFF_HB + HSIZE;
constexpr size_t OFF_FZX  = OFF_FX + 2 * FX_C;
constexpr size_t OFF_FS   = OFF_FZX + 2 * FZX_C;
constexpr size_t OFF_G    = OFF_FS + 2 * FS_C;
constexpr size_t OFF_ST   = OFF_G + 2 * FS_C;     // (legacy, unused)
constexpr size_t OFF_SC   = OFF_ST + 256;         // 4 layers x (scale[32], shift[32])
constexpr size_t OFF_TWXF = OFF_SC + 256;         // [x=96][k=12] cplx, e^{-i}
constexpr size_t OFF_TWZF = OFF_TWXF + 2 * 96 * 12;   // [z=96][k=24]
constexpr size_t OFF_TWSF = OFF_TWZF + 2 * 96 * 24;   // [s=32][k=16], includes 1/294912
constexpr size_t OFF_TWSI = OFF_TWSF + 2 * 32 * 16;   // [k=16][s=32] cplx, e^{+i}
constexpr size_t OFF_TWZI = OFF_TWSI + 2 * 16 * 32;   // [k=24][z=96]
constexpr size_t OFF_TWXI = OFF_TWZI + 2 * 24 * 96;   // [k=12][x=96]
// BN-stat PARTIALS: 4 layers x 64 slots x (sum[32],sumsq[32]) = 16384 floats.
// Hashed by (blockIdx & 63) (r6 post-mortem: single-copy same-address atomics
// from 6144 blocks serialized in L2 -> 331us; hashing fixed it to 90us, r7).
constexpr size_t OFF_STP  = OFF_TWXI + 2 * 12 * 96;

__global__ void k_init_tw(float* ws) {
  const double TWO_PI = 6.283185307179586476925286766559;
  int t = threadIdx.x;
  float2* twxf = (float2*)(ws + OFF_TWXF);
  for (int i = t; i < 96 * 12; i += 256) {
    int x = i / 12, k = i % 12;
    double a = -TWO_PI * (double)((k * x) % 96) / 96.0;
    twxf[i] = make_float2((float)cos(a), (float)sin(a));
  }
  float2* twzf = (float2*)(ws + OFF_TWZF);
  for (int i = t; i < 96 * 24; i += 256) {
    int z = i / 24, k = i % 24;
    double a = -TWO_PI * (double)((k * z) % 96) / 96.0;
    twzf[i] = make_float2((float)cos(a), (float)sin(a));
  }
  float2* twsf = (float2*)(ws + OFF_TWSF);
  const double SC = 1.0 / (double)(NS * NZ * NX);  // fftn norm='forward'
  for (int i = t; i < 32 * 16; i += 256) {
    int s = i / 16, k = i % 16;
    int f = (k < 8) ? k : k + 16;                  // s-modes 0..7, 24..31
    double a = -TWO_PI * (double)((f * s) % 32) / 32.0;
    twsf[i] = make_float2((float)(cos(a) * SC), (float)(sin(a) * SC));
  }
  float2* twsi = (float2*)(ws + OFF_TWSI);
  for (int i = t; i < 16 * 32; i += 256) {
    int k = i / 32, s = i % 32;
    int f = (k < 8) ? k : k + 16;
    double a = TWO_PI * (double)((f * s) % 32) / 32.0;
    twsi[i] = make_float2((float)cos(a), (float)sin(a));
  }
  float2* twzi = (float2*)(ws + OFF_TWZI);
  for (int i = t; i < 24 * 96; i += 256) {
    int k = i / 96, z = i % 96;
    int f = (k < 12) ? k : k + 72;                 // z-modes 0..11, 84..95
    double a = TWO_PI * (double)((f * z) % 96) / 96.0;
    twzi[i] = make_float2((float)cos(a), (float)sin(a));
  }
  float2* twxi = (float2*)(ws + OFF_TWXI);
  for (int i = t; i < 12 * 96; i += 256) {
    int k = i / 96, x = i % 96;
    double a = TWO_PI * (double)((k * x) % 96) / 96.0;
    twxi[i] = make_float2((float)cos(a), (float)sin(a));
  }
}

__global__ void k_zero_stats(float* stp) {
  stp[blockIdx.x * 256 + threadIdx.x] = 0.f;   // 64 blocks x 256 = 16384 floats
}

// Fused dftx+dftz. block = (b,c,s). Stage BN(h) plane in LDS (coalesced, +97
// pad), dftx with 6 complex reg-accumulators per thread + SCALAR twiddles
// (half = t>>7 is wave-uniform), dftz with dual accumulators.
// Layer 0 (use_bn==0): h is never materialized -- compute the plane from the
// xin (b,s) slab on the fly (h = x0*w0[c]+x1*w1[c]+b[c]; xin is 4.7MB total,
// L2-resident across the 32 channel-blocks that re-read each slab).
// Output fzx[bcs][kz*12+kx] contiguous per block.
__global__ __launch_bounds__(256) void k_fwd(const float* __restrict__ h, const float* __restrict__ xin,
                      const float* __restrict__ fc0w, const float* __restrict__ fc0b,
                      float2* __restrict__ fzx,
                      const float2* __restrict__ twxf, const float2* __restrict__ twzf,
                      const float* __restrict__ sc, int use_bn) {
  __shared__ float  sh_h[96 * 97];     // 37.2 KB
  __shared__ float2 sh_fx[96 * 12];    // 9 KB  [z][kx]
  int t = threadIdx.x;
  int bcs = blockIdx.x;               // 2048 = 64 bc * 32 s
  int s = bcs & 31;
  int bc = bcs >> 5;
  int c = bc & 31;
  int b = bc >> 5;
  if (use_bn) {
    float scale = sc[c];
    float shift = sc[32 + c];
    const float* hp = h + (size_t)bc * CHS + (size_t)s * (NZ * NX);
    for (int i = t; i < NZ * NX; i += 256) {
      float v = hp[i];                   // coalesced row-major
      v = v * scale + shift;
      v = v >= 0.f ? v : v * 0.1f;
      sh_h[(i / 96) * 97 + (i % 96)] = v;
    }
  } else {
    // layer 0: expand fc0 on the fly from xin (no BN, no leaky)
    float w0 = fc0w[c], w1v = fc0w[C_ + c], bb = fc0b[c];
    const float2* xp = (const float2*)xin + ((size_t)b * NS + s) * (NZ * NX);
    for (int i = t; i < NZ * NX; i += 256) {
      float2 xv = xp[i];                 // coalesced, L2-hot
      sh_h[(i / 96) * 97 + (i % 96)] = xv.x * w0 + xv.y * w1v + bb;
    }
  }
  __syncthreads();
  // dftx: waves 0-1 -> kx 0..5, waves 2-3 -> kx 6..11; z = t&127 (<96 active)
  {
    int half = __builtin_amdgcn_readfirstlane(t >> 7);   // wave-uniform
    int z = t & 127;
    if (z < 96) {
      float ar[6], ai[6];
      #pragma unroll
      for (int j = 0; j < 6; ++j) { ar[j] = 0.f; ai[j] = 0.f; }
      const float2* twx = twxf + half * 6;
      const float* row = sh_h + z * 97;
      for (int x = 0; x < 96; ++x) {
        float v = row[x];              // 1 ds_read per 12 FMAs
        #pragma unroll
        for (int j = 0; j < 6; ++j) {
          float2 w = twx[x * 12 + j];  // wave-uniform -> s_load (K$-hot)
          ar[j] += v * w.x; ai[j] += v * w.y;
        }
      }
      #pragma unroll
      for (int j = 0; j < 6; ++j)
        sh_fx[z * 12 + half * 6 + j] = make_float2(ar[j], ai[j]);
    }
  }
  __syncthreads();
  // dftz: item = (kz,kx), 288 items; dual accumulators, tw L1-hot vector loads
  float2* outp = fzx + (size_t)bcs * 288;
  for (int it = t; it < 288; it += 256) {
    int kx = it % 12, kz = it / 12;
    float ar0 = 0.f, ai0 = 0.f, ar1 = 0.f, ai1 = 0.f;
    for (int z = 0; z < 96; z += 2) {
      float2 v0 = sh_fx[z * 12 + kx];
      float2 w0 = twzf[z * 24 + kz];
      float2 v1 = sh_fx[(z + 1) * 12 + kx];
      float2 w1 = twzf[(z + 1) * 24 + kz];
      ar0 += v0.x * w0.x - v0.y * w0.y;
      ai0 += v0.x * w0.y + v0.y * w0.x;
      ar1 += v1.x * w1.x - v1.y * w1.y;
      ai1 += v1.x * w1.y + v1.y * w1.x;
    }
    outp[it] = make_float2(ar0 + ar1, ai0 + ai1);   // coalesced
  }
}

// Fs[bc][ks*288+kzkx] = sum_s Fzx[bc][s][kzkx] * tw; thread per output.
__global__ __launch_bounds__(256) void k_dfts(const float2* __restrict__ fzx, float2* __restrict__ fs,
                       const float2* __restrict__ tw) {
  int tid = blockIdx.x * 256 + threadIdx.x;   // 294,912
  int kzkx = tid % 288;
  int ks = (tid / 288) & 15;
  int bc = tid / 4608;
  const float2* src = fzx + (size_t)bc * (32 * 288) + kzkx;
  float ar = 0.f, ai = 0.f;
  #pragma unroll 8
  for (int s = 0; s < 32; ++s) {
    float2 v = src[s * 288];
    float2 w = tw[s * 16 + ks];
    ar += v.x * w.x - v.y * w.y;
    ai += v.x * w.y + v.y * w.x;
  }
  fs[(size_t)bc * 4608 + ks * 288 + kzkx] = make_float2(ar, ai);
}

// G[b][o][fidx] = sum_i Fs[b][i][fidx] * w[l,q,i,o,mode]; lanes = consecutive modes
__global__ __launch_bounds__(256) void k_mix(const float2* __restrict__ fs, const float* __restrict__ spec,
                      int l, float2* __restrict__ g) {
  int tid = blockIdx.x * 256 + threadIdx.x;   // 147,456 = 4q * 32o * 1152m
  int m = tid % 1152;
  int o = (tid / 1152) & 31;
  int q = tid / 36864;
  int m1 = m / 144, r = m - m1 * 144, m2 = r / 12, m3 = r - m2 * 12;
  int ks = m1 + (q & 1) * 8;
  int kz = m2 + ((q >> 1) & 1) * 12;
  int fidx = (ks * KZ + kz) * KX + m3;
  const float2* w2 = (const float2*)spec;
  size_t widx = ((size_t)(l * 4 + q) * 1024 + o) * 1152 + m;   // + i*36864 per i
  const float2* f0 = fs + fidx;                                 // + i*4608 per i
  const float2* f1 = fs + (size_t)C_ * 4608 + fidx;
  float a0r = 0.f, a0i = 0.f, a1r = 0.f, a1i = 0.f;
  #pragma unroll 4
  for (int i = 0; i < C_; ++i) {
    float2 w = w2[widx];  widx += 36864;
    float2 v0 = f0[(size_t)i * 4608];
    float2 v1 = f1[(size_t)i * 4608];
    a0r += v0.x * w.x - v0.y * w.y;  a0i += v0.x * w.y + v0.y * w.x;
    a1r += v1.x * w.x - v1.y * w.y;  a1i += v1.x * w.y + v1.y * w.x;
  }
  g[(size_t)o * 4608 + fidx] = make_float2(a0r, a0i);
  g[(size_t)(C_ + o) * 4608 + fidx] = make_float2(a1r, a1i);
}

// Fused idfts+idftz. block = (bo, s): stage g[bo] (36.9 KB) in LDS, compute
// gs slice [288] in LDS (16-term s-inverse, twiddles via s_load since s is
// block-uniform), then gz row [z=96][kx=12] (24-term z-inverse, twzi L1-hot).
// Eliminates the gs global round-trip and one launch per layer (r6 ledger:
// ~-20us/layer vs separate idfts+idftz). LDS 39.2 KB -> 4 blocks/CU.
__global__ __launch_bounds__(256) void k_idft_sz(const float2* __restrict__ g, float2* __restrict__ gz,
                        const float2* __restrict__ twsi, const float2* __restrict__ twzi) {
  __shared__ float2 sh_g[4608];    // 36.9 KB, this bo's full G
  __shared__ float2 sh_gs[288];    // 2.3 KB, gs slice for this s
  int t = threadIdx.x;
  int bo = blockIdx.x >> 5;
  int s  = blockIdx.x & 31;
  const float2* gsrc = g + (size_t)bo * 4608;
  for (int i = t; i < 4608; i += 256) sh_g[i] = gsrc[i];   // coalesced, L2-hot
  __syncthreads();
  // gs[kzkx] = sum_ks sh_g[ks*288+kzkx] * twsi[ks*32+s]  (twsi: s_load)
  for (int it = t; it < 288; it += 256) {
    float ar = 0.f, ai = 0.f;
    #pragma unroll
    for (int ks = 0; ks < 16; ++ks) {
      float2 v = sh_g[ks * 288 + it];
      float2 w = twsi[ks * 32 + s];
      ar += v.x * w.x - v.y * w.y;
      ai += v.x * w.y + v.y * w.x;
    }
    sh_gs[it] = make_float2(ar, ai);
  }
  __syncthreads();
  // gz[z][kx] = sum_kz sh_gs[kz*12+kx] * twzi[kz*96+z]
  float2* outp = gz + (size_t)(bo * 32 + s) * 1152;
  for (int it = t; it < 1152; it += 256) {
    int kx = it % 12, z = it / 12;
    float ar = 0.f, ai = 0.f;
    #pragma unroll 8
    for (int kz = 0; kz < 24; ++kz) {
      float2 v = sh_gs[kz * 12 + kx];
      float2 w = twzi[kz * 96 + z];
      ar += v.x * w.x - v.y * w.y;
      ai += v.x * w.y + v.y * w.x;
    }
    outp[it] = make_float2(ar, ai);    // coalesced
  }
}

// a[b][o][s][z][x] = Re(sum_kx Gz e^{+..}) + sum_i ww[o][i] h_bn[b][i][s][z][x] + wb[o]
// r11: VALU-trim. r10 profile: VALU-issue-bound (VALUBusy 55%, BW 19%).
// (1) h tile TRANSPOSED to [x][c], stride 34 (even -> float2-aligned for
//     even c; banks (2x+c)%32 = 2-way aliasing, free per m136) -> the
//     ww-loop reads 16x ds_read_b64 instead of 32x stride-96 ds_read_b32.
// (2) float4 h staging: 3 iterations (c=i/24, 24 float4/row, coalesced
//     384B runs) vs 32 scalar iterations of magic-divide+addr overhead.
// (3) float4 gz staging (192 loads, 1 iteration).
// BN-tail scratch uses the same transposed layout (write banks 2-way,
// tail reads <=2-way). Slot-hashed atomics unchanged (r7).
__global__ __launch_bounds__(256) void k_idftx_fuse(const float2* __restrict__ gz, const float* __restrict__ hsrc,
                             const float* __restrict__ xin, const float* __restrict__ fc0w,
                             const float* __restrict__ fc0b,
                             const float* __restrict__ ww, const float* __restrict__ wb,
                             const float2* __restrict__ twxi, const float* __restrict__ sc,
                             int use_bn, float* __restrict__ adst, float* __restrict__ stp) {
  __shared__ float  sh_ht[NX * 34];   // 12.75 KB, transposed [x][c]; later [x][o] scratch
  __shared__ float2 sh_g[C_ * KX];    // 3 KB, this (b,s,z)'s 32x12 gz fragments
  int blk = blockIdx.x;               // z fastest
  int z = blk % NZ, s = (blk / NZ) % NS, b = blk / (NZ * NS);
  int t = threadIdx.x;
  size_t rowbase = ((size_t)b * C_) * CHS + (size_t)s * (NZ * NX) + (size_t)z * NX;
  if (use_bn) {
    // float4 staging: 768 items = 32 c x 24 float4-per-row
    for (int i4 = t; i4 < C_ * 24; i4 += 256) {
      int c = i4 / 24, xf = i4 % 24;
      float4 v4 = *(const float4*)(hsrc + rowbase + (size_t)c * CHS + xf * 4);
      float scl = sc[c], shf = sc[32 + c];
      float vv[4] = {v4.x, v4.y, v4.z, v4.w};
      #pragma unroll
      for (int e = 0; e < 4; ++e) {
        float v = vv[e] * scl + shf;
        v = v >= 0.f ? v : v * 0.1f;
        sh_ht[(xf * 4 + e) * 34 + c] = v;
      }
    }
  } else {
    // layer 0: expand fc0 from xin row (no BN, no leaky); transposed write
    const float2* xp = (const float2*)xin + (((size_t)b * NS + s) * NZ + z) * NX;
    for (int i = t; i < C_ * NX; i += 256) {
      int c = i / NX, x = i % NX;
      float2 xv = xp[x];               // L1-hot (row re-read across c)
      sh_ht[x * 34 + c] = xv.x * fc0w[c] + xv.y * fc0w[C_ + c] + fc0b[c];
    }
  }
  // stage gz as float4: 192 loads (o = t/6, f = t%6); 96B rows, 16B-aligned
  if (t < 192) {
    int o = t / 6, f = t % 6;
    const float4* gp = (const float4*)(gz + (((size_t)(b * C_ + o) * NS + s) * NZ + z) * KX);
    ((float4*)sh_g)[o * 6 + f] = gp[f];
  }
  __syncthreads();
  int x = t & 127;
  int og = __builtin_amdgcn_readfirstlane(t >> 7);   // wave-uniform
  float acc[16];
  if (x < NX) {
    float2 tw[KX];
    #pragma unroll
    for (int k = 0; k < KX; ++k) tw[k] = twxi[k * NX + x];
    #pragma unroll
    for (int j = 0; j < 16; ++j) {
      int o = og * 16 + j;
      float a = wb[o];                                  // s_load
      const float2* gp = sh_g + o * KX;                 // LDS broadcast (free)
      #pragma unroll
      for (int k = 0; k < KX; ++k) {
        float2 gv = gp[k];
        a += gv.x * tw[k].x - gv.y * tw[k].y;
      }
      acc[j] = a;
    }
    const float* wwb = ww + og * 16 * C_;
    #pragma unroll 4
    for (int i2 = 0; i2 < 16; ++i2) {
      float2 hv = *(const float2*)(sh_ht + x * 34 + 2 * i2);  // ds_read_b64
      #pragma unroll
      for (int j = 0; j < 16; ++j) acc[j] += wwb[j * C_ + 2 * i2] * hv.x;     // s_load
      #pragma unroll
      for (int j = 0; j < 16; ++j) acc[j] += wwb[j * C_ + 2 * i2 + 1] * hv.y; // s_load
    }
    #pragma unroll
    for (int j = 0; j < 16; ++j)
      adst[rowbase + (size_t)(og * 16 + j) * CHS + x] = acc[j];
  }
  // ---- fused BN stats: reduce raw acc over this block's 96 x per channel ----
  __syncthreads();                    // everyone done reading sh_ht
  if (x < NX) {
    #pragma unroll
    for (int j = 0; j < 16; ++j) sh_ht[x * 34 + og * 16 + j] = acc[j];
  }
  __syncthreads();
  {
    int o = t >> 3, ch = t & 7;       // 32 channels x 8 chunks of 12
    float s1 = 0.f, s2 = 0.f;
    #pragma unroll
    for (int k = 0; k < 12; ++k) {
      float v = sh_ht[(ch * 12 + k) * 34 + o];
      s1 += v; s2 += v * v;
    }
    s1 += __shfl_down(s1, 4);  s2 += __shfl_down(s2, 4);
    s1 += __shfl_down(s1, 2);  s2 += __shfl_down(s2, 2);
    s1 += __shfl_down(s1, 1);  s2 += __shfl_down(s2, 1);
    if (ch == 0) {
      float* slot = stp + (size_t)(blk & 63) * 64;     // hashed partial copy
      atomicAdd(&slot[o], s1);
      atomicAdd(&slot[32 + o], s2);
    }
  }
}

// reduce 64 partial slots -> (scale, shift) for this layer
__global__ void k_bnfinal(const float* __restrict__ stp, const float* __restrict__ g,
                          const float* __restrict__ bb, float* __restrict__ sc) {
  __shared__ float tot[64];
  int t = threadIdx.x;                // 64 threads
  float s = 0.f;
  for (int slot = 0; slot < 64; ++slot) s += stp[slot * 64 + t];
  tot[t] = s;
  __syncthreads();
  if (t < 32) {
    const float N = (float)NPTS;
    float mean = tot[t] / N;
    float var = tot[32 + t] / N - mean * mean;
    float inv = rsqrtf(var + 1e-5f);
    float scale = inv * g[t];
    sc[t] = scale;
    sc[32 + t] = bb[t] - mean * scale;
  }
}

// MLP, LDS-activation + scalar-weight design, 512-thread blocks (8 waves).
// r9 scalar form (r10's float2 LDS reads were neutral-to-negative -> the
// residual is NOT LDS-issue-bound; reverted). Measured: 256thr=492us,
// 1024thr=593us, 512thr=380us. 8 sub-launches for rocprof visibility.
__global__ __launch_bounds__(512, 6) void k_mlp(
    const float* __restrict__ h, const float* __restrict__ xin,
    const float* __restrict__ sc, int blk0,
    const float* __restrict__ w1, const float* __restrict__ b1,
    const float* __restrict__ w2, const float* __restrict__ b2,
    const float* __restrict__ w3, const float* __restrict__ b3,
    const float* __restrict__ w4, const float* __restrict__ b4,
    const float* __restrict__ w5, const float* __restrict__ b5,
    const float* __restrict__ w7, const float* __restrict__ b7,
    float* __restrict__ out) {
  __shared__ float A[64 * 65];    // 16.6 KB (32/64-wide activations)
  __shared__ float Bf[64 * 129];  // 33 KB  (128/32-wide activations)
  __shared__ float P[64 * 9];     // 2.3 KB (fc7 per-wave partials)
  int t = threadIdx.x;
  int p = t & 63;                                      // point within block
  int q = __builtin_amdgcn_readfirstlane(t >> 6);      // wave id 0..7, uniform
  int pt0 = (blockIdx.x + blk0) * 64;

  // phase 0: A[p][c] = leaky(BN3(h)); lanes -> consecutive points (coalesced)
  for (int i = t; i < 64 * 32; i += 512) {
    int c = i >> 6, pp = i & 63;
    int pt = pt0 + pp;
    size_t base = (size_t)(pt / CHS) * C_ * CHS + (pt % CHS);
    float v = h[base + (size_t)c * CHS];
    v = v * sc[c] + sc[32 + c];                        // sc via s_load
    A[pp * 65 + c] = v >= 0.f ? v : 0.1f * v;
  }
  __syncthreads();

  // phase 1: fc1 (32->128): A -> Bf, 16 outputs/thread (m0 = q*16)
  {
    const int m0 = q * 16;
    float acc[16];
    #pragma unroll
    for (int j = 0; j < 16; ++j) acc[j] = b1[m0 + j];
    const float* arow = A + p * 65;
    #pragma unroll 4
    for (int k = 0; k < 32; ++k) {
      float a = arow[k];
      const float* wr = w1 + k * 128 + m0;             // uniform -> s_load
      #pragma unroll
      for (int j = 0; j < 16; ++j) acc[j] += a * wr[j];
    }
    float* brow = Bf + p * 129 + m0;
    #pragma unroll
    for (int j = 0; j < 16; ++j) {
      float v = acc[j];
      brow[j] = v >= 0.f ? v : 0.1f * v;
    }
  }
  __syncthreads();

  // phase 2: fc2 (128->64): Bf -> A, 8 outputs/thread (m0 = q*8)
  {
    const int m0 = q * 8;
    float acc[8];
    #pragma unroll
    for (int j = 0; j < 8; ++j) acc[j] = b2[m0 + j];
    const float* brow = Bf + p * 129;
    #pragma unroll 4
    for (int k = 0; k < 128; ++k) {
      float a = brow[k];
      const float* wr = w2 + k * 64 + m0;              // s_load
      #pragma unroll
      for (int j = 0; j < 8; ++j) acc[j] += a * wr[j];
    }
    float* arow = A + p * 65 + m0;
    #pragma unroll
    for (int j = 0; j < 8; ++j) {
      float v = acc[j];
      arow[j] = v >= 0.f ? v : 0.1f * v;
    }
  }
  __syncthreads();

  // phase 3: fc3 (64->32): A -> Bf (low cols), 4 outputs/thread (m0 = q*4)
  {
    const int m0 = q * 4;
    float acc[4];
    #pragma unroll
    for (int j = 0; j < 4; ++j) acc[j] = b3[m0 + j];
    const float* arow = A + p * 65;
    #pragma unroll 4
    for (int k = 0; k < 64; ++k) {
      float a = arow[k];
      const float* wr = w3 + k * 32 + m0;              // s_load
      #pragma unroll
      for (int j = 0; j < 4; ++j) acc[j] += a * wr[j];
    }
    float* brow = Bf + p * 129 + m0;
    #pragma unroll
    for (int j = 0; j < 4; ++j) {
      float v = acc[j];
      brow[j] = v >= 0.f ? v : 0.1f * v;
    }
  }
  __syncthreads();

  // phase 4: fc4 (32->64): Bf -> A, 8 outputs/thread (m0 = q*8)
  {
    const int m0 = q * 8;
    float acc[8];
    #pragma unroll
    for (int j = 0; j < 8; ++j) acc[j] = b4[m0 + j];
    const float* brow = Bf + p * 129;
    #pragma unroll 4
    for (int k = 0; k < 32; ++k) {
      float a = brow[k];
      const float* wr = w4 + k * 64 + m0;              // s_load
      #pragma unroll
      for (int j = 0; j < 8; ++j) acc[j] += a * wr[j];
    }
    float* arow = A + p * 65 + m0;
    #pragma unroll
    for (int j = 0; j < 8; ++j) {
      float v = acc[j];
      arow[j] = v >= 0.f ? v : 0.1f * v;
    }
  }
  __syncthreads();

  // phase 5: fc5 (64->128) fused with fc7 (128->1): per-wave partial dot
  {
    const int m0 = q * 16;
    float acc[16];
    #pragma unroll
    for (int j = 0; j < 16; ++j) acc[j] = b5[m0 + j];
    const float* arow = A + p * 65;
    #pragma unroll 4
    for (int k = 0; k < 64; ++k) {
      float a = arow[k];
      const float* wr = w5 + k * 128 + m0;             // s_load
      #pragma unroll
      for (int j = 0; j < 16; ++j) acc[j] += a * wr[j];
    }
    float partial = 0.f;
    #pragma unroll
    for (int j = 0; j < 16; ++j) {
      float v = acc[j];
      v = v >= 0.f ? v : 0.1f * v;                     // leaky(fc5)
      partial += v * w7[m0 + j];                       // s_load
    }
    P[p * 9 + q] = partial;
  }
  __syncthreads();

  // phase 6: wave 0 reduces the 8 partials, applies mask, stores
  if (q == 0) {
    int pt = pt0 + p;
    float acc = b7[0];
    #pragma unroll
    for (int j = 0; j < 8; ++j) acc += P[p * 9 + j];
    float T0 = xin[2 * pt + 1];
    float mask = (T0 < 0.01f) ? T0 : 1.0f;
    int z = (pt / NX) % NZ;
    if (z < 2) mask = 0.f;
    out[pt] = acc * mask;
  }
}

__global__ void k_loss(const float* __restrict__ tau, const float* __restrict__ xin,
                       const float* __restrict__ y, float* __restrict__ loss) {
  int pt = blockIdx.x * 256 + threadIdx.x;
  int x = pt % NX, z = (pt / NX) % NZ;
  float tpx = (x < NX - 1) ? tau[pt + 1] : 0.f;
  float tmx = (x > 0) ? tau[pt - 1] : 0.f;
  float tpz = (z < NZ - 1) ? tau[pt + NX] : 0.f;
  float tmz = (z > 0) ? tau[pt - NX] : 0.f;
  float Tpx = (x < NX - 1) ? xin[2 * (pt + 1) + 1] : 0.f;
  float Tmx = (x > 0) ? xin[2 * (pt - 1) + 1] : 0.f;
  float Tpz = (z < NZ - 1) ? xin[2 * (pt + NX) + 1] : 0.f;
  float Tmz = (z > 0) ? xin[2 * (pt - NX) + 1] : 0.f;
  float dx = (tpx - tmx) * 50.f + (Tpx - Tmx) * 50.f;
  float dz = (tpz - tmz) * 50.f + (Tpz - Tmz) * 50.f;
  loss[pt] = dx * dx + dz * dz - y[pt];
}

extern "C" void kernel_launch(void* const* d_in, const int* in_sizes, int n_in,
                              void* d_out, int out_size, void* d_ws, size_t ws_size,
                              hipStream_t stream) {
  (void)in_sizes; (void)n_in; (void)out_size; (void)ws_size;
  const float* xin    = (const float*)d_in[0];
  const float* y      = (const float*)d_in[1];
  const float* fc0_w  = (const float*)d_in[2];
  const float* fc0_b  = (const float*)d_in[3];
  const float* spec_w = (const float*)d_in[4];
  const float* w_w    = (const float*)d_in[5];
  const float* w_b    = (const float*)d_in[6];
  const float* bn_g   = (const float*)d_in[7];
  const float* bn_b   = (const float*)d_in[8];
  const float* fc1_w  = (const float*)d_in[9];
  const float* fc1_b  = (const float*)d_in[10];
  const float* fc2_w  = (const float*)d_in[11];
  const float* fc2_b  = (const float*)d_in[12];
  const float* fc3_w  = (const float*)d_in[13];
  const float* fc3_b  = (const float*)d_in[14];
  const float* fc4_w  = (const float*)d_in[15];
  const float* fc4_b  = (const float*)d_in[16];
  const float* fc5_w  = (const float*)d_in[17];
  const float* fc5_b  = (const float*)d_in[18];
  const float* fc7_w  = (const float*)d_in[19];
  const float* fc7_b  = (const float*)d_in[20];
  float* ws  = (float*)d_ws;
  float* out = (float*)d_out;

  k_init_tw<<<1, 256, 0, stream>>>(ws);
  k_zero_stats<<<64, 256, 0, stream>>>(ws + OFF_STP);
  // NOTE: no k_fc0 -- layer 0 expands fc0 on the fly in k_fwd/k_idftx_fuse.

  float* hsrc = ws + OFF_HA;   // unwritten for l=0; layer-0 kernels don't read it
  float* hdst = ws + OFF_HB;
  for (int l = 0; l < 4; ++l) {
    const float* sc_prev = ws + OFF_SC + (size_t)(l - 1) * 64;  // only read if l>0
    int use_bn = (l > 0) ? 1 : 0;
    float* stp_l = ws + OFF_STP + (size_t)l * 4096;
    k_fwd<<<B_ * C_ * NS, 256, 0, stream>>>(hsrc, xin, fc0_w, fc0_b,
                                            (float2*)(ws + OFF_FZX),
                                            (const float2*)(ws + OFF_TWXF),
                                            (const float2*)(ws + OFF_TWZF), sc_prev, use_bn);
    k_dfts<<<1152, 256, 0, stream>>>((const float2*)(ws + OFF_FZX), (float2*)(ws + OFF_FS),
                                     (const float2*)(ws + OFF_TWSF));
    k_mix<<<576, 256, 0, stream>>>((const float2*)(ws + OFF_FS), spec_w, l,
                                   (float2*)(ws + OFF_G));
    k_idft_sz<<<64 * 32, 256, 0, stream>>>((const float2*)(ws + OFF_G), (float2*)(ws + OFF_FX),
                                           (const float2*)(ws + OFF_TWSI),
                                           (const float2*)(ws + OFF_TWZI));
    k_idftx_fuse<<<B_ * NS * NZ, 256, 0, stream>>>((const float2*)(ws + OFF_FX), hsrc,
                                                   xin, fc0_w, fc0_b,
                                                   w_w + (size_t)l * C_ * C_, w_b + (size_t)l * C_,
                                                   (const float2*)(ws + OFF_TWXI), sc_prev,
                                                   use_bn, hdst, stp_l);
    k_bnfinal<<<1, 64, 0, stream>>>(stp_l, bn_g + (size_t)l * C_,
                                    bn_b + (size_t)l * C_, ws + OFF_SC + (size_t)l * 64);
    float* tmp = hsrc; hsrc = hdst; hdst = tmp;
  }

  // 8 sub-launches of 1152 blocks: keeps per-dispatch dur small so spectral
  // kernels stay visible in the rocprof top-5 (diagnostic; ~15us cost)
  for (int part = 0; part < 8; ++part) {
    k_mlp<<<1152, 512, 0, stream>>>(hsrc, xin, ws + OFF_SC + 192, part * 1152,
                                    fc1_w, fc1_b, fc2_w, fc2_b, fc3_w, fc3_b,
                                    fc4_w, fc4_b, fc5_w, fc5_b, fc7_w, fc7_b, out);
  }
  k_loss<<<NPTS / 256, 256, 0, stream>>>(out, xin, y, out + NPTS);
}

// Round 12
// 1365.213 us; speedup vs baseline: 1.0383x; 1.0106x over previous
//
#include <hip/hip_runtime.h>
#include <math.h>

constexpr int B_ = 2, C_ = 32, NS = 32, NZ = 96, NX = 96;
constexpr int KS = 16, KZ = 24, KX = 12;          // kept mode counts (s, z, x)
constexpr int NPTS = B_ * NS * NZ * NX;           // 589824
constexpr int CHS  = NS * NZ * NX;                // 294912 (per-channel stride)
constexpr size_t HSIZE = (size_t)B_ * C_ * CHS;   // 18,874,368 floats

constexpr size_t FX_C  = (size_t)B_ * C_ * NS * KX * NZ;  // 2,359,296 cplx (gz)
constexpr size_t FZX_C = (size_t)B_ * C_ * KZ * KX * NS;  //   589,824 cplx (fzx)
constexpr size_t FS_C  = (size_t)B_ * C_ * KS * KZ * KX;  //   294,912 cplx

// workspace offsets (floats). gz overlays FX.
constexpr size_t OFF_HA   = 0;
constexpr size_t OFF_HB   = OFF_HA + HSIZE;
constexpr size_t OFF_FX   = OFF_HB + HSIZE;
constexpr size_t OFF_FZX  = OFF_FX + 2 * FX_C;
constexpr size_t OFF_FS   = OFF_FZX + 2 * FZX_C;
constexpr size_t OFF_G    = OFF_FS + 2 * FS_C;
constexpr size_t OFF_ST   = OFF_G + 2 * FS_C;     // (legacy, unused)
constexpr size_t OFF_SC   = OFF_ST + 256;         // 4 layers x (scale[32], shift[32])
constexpr size_t OFF_TWXF = OFF_SC + 256;         // [x=96][k=12] cplx, e^{-i}
constexpr size_t OFF_TWZF = OFF_TWXF + 2 * 96 * 12;   // [z=96][k=24]
constexpr size_t OFF_TWSF = OFF_TWZF + 2 * 96 * 24;   // [s=32][k=16], includes 1/294912
constexpr size_t OFF_TWSI = OFF_TWSF + 2 * 32 * 16;   // [k=16][s=32] cplx, e^{+i}
constexpr size_t OFF_TWZI = OFF_TWSI + 2 * 16 * 32;   // [k=24][z=96]
constexpr size_t OFF_TWXI = OFF_TWZI + 2 * 24 * 96;   // [k=12][x=96]
// BN-stat PARTIALS: 4 layers x 64 slots x (sum[32],sumsq[32]) = 16384 floats.
// Hashed by (blockIdx & 63) (r6 post-mortem: single-copy same-address atomics
// from 6144 blocks serialized in L2 -> 331us; hashing fixed it to 90us, r7).
constexpr size_t OFF_STP  = OFF_TWXI + 2 * 12 * 96;

__global__ void k_init_tw(float* ws) {
  const double TWO_PI = 6.283185307179586476925286766559;
  int t = threadIdx.x;
  float2* twxf = (float2*)(ws + OFF_TWXF);
  for (int i = t; i < 96 * 12; i += 256) {
    int x = i / 12, k = i % 12;
    double a = -TWO_PI * (double)((k * x) % 96) / 96.0;
    twxf[i] = make_float2((float)cos(a), (float)sin(a));
  }
  float2* twzf = (float2*)(ws + OFF_TWZF);
  for (int i = t; i < 96 * 24; i += 256) {
    int z = i / 24, k = i % 24;
    double a = -TWO_PI * (double)((k * z) % 96) / 96.0;
    twzf[i] = make_float2((float)cos(a), (float)sin(a));
  }
  float2* twsf = (float2*)(ws + OFF_TWSF);
  const double SC = 1.0 / (double)(NS * NZ * NX);  // fftn norm='forward'
  for (int i = t; i < 32 * 16; i += 256) {
    int s = i / 16, k = i % 16;
    int f = (k < 8) ? k : k + 16;                  // s-modes 0..7, 24..31
    double a = -TWO_PI * (double)((f * s) % 32) / 32.0;
    twsf[i] = make_float2((float)(cos(a) * SC), (float)(sin(a) * SC));
  }
  float2* twsi = (float2*)(ws + OFF_TWSI);
  for (int i = t; i < 16 * 32; i += 256) {
    int k = i / 32, s = i % 32;
    int f = (k < 8) ? k : k + 16;
    double a = TWO_PI * (double)((f * s) % 32) / 32.0;
    twsi[i] = make_float2((float)cos(a), (float)sin(a));
  }
  float2* twzi = (float2*)(ws + OFF_TWZI);
  for (int i = t; i < 24 * 96; i += 256) {
    int k = i / 96, z = i % 96;
    int f = (k < 12) ? k : k + 72;                 // z-modes 0..11, 84..95
    double a = TWO_PI * (double)((f * z) % 96) / 96.0;
    twzi[i] = make_float2((float)cos(a), (float)sin(a));
  }
  float2* twxi = (float2*)(ws + OFF_TWXI);
  for (int i = t; i < 12 * 96; i += 256) {
    int k = i / 96, x = i % 96;
    double a = TWO_PI * (double)((k * x) % 96) / 96.0;
    twxi[i] = make_float2((float)cos(a), (float)sin(a));
  }
}

__global__ void k_zero_stats(float* stp) {
  stp[blockIdx.x * 256 + threadIdx.x] = 0.f;   // 64 blocks x 256 = 16384 floats
}

// Fused dftx+dftz. block = (b,c,s). Stage BN(h) plane in LDS (coalesced, +97
// pad), dftx with 6 complex reg-accumulators per thread + SCALAR twiddles
// (half = t>>7 is wave-uniform), dftz with dual accumulators.
// r12: float4 global staging (r11 pattern proven on idftx: wide loads + 1
// divide per 4 elements instead of per element). LDS writes stay scalar to
// preserve the conflict-free stride-97 rows (r10 lesson: don't vectorize the
// LDS side). Layer 0 (use_bn==0): h never materialized -- expand fc0 from
// the xin slab (L2-resident), float4 = 2 points.
__global__ __launch_bounds__(256) void k_fwd(const float* __restrict__ h, const float* __restrict__ xin,
                      const float* __restrict__ fc0w, const float* __restrict__ fc0b,
                      float2* __restrict__ fzx,
                      const float2* __restrict__ twxf, const float2* __restrict__ twzf,
                      const float* __restrict__ sc, int use_bn) {
  __shared__ float  sh_h[96 * 97];     // 37.2 KB
  __shared__ float2 sh_fx[96 * 12];    // 9 KB  [z][kx]
  int t = threadIdx.x;
  int bcs = blockIdx.x;               // 2048 = 64 bc * 32 s
  int s = bcs & 31;
  int bc = bcs >> 5;
  int c = bc & 31;
  int b = bc >> 5;
  if (use_bn) {
    float scale = sc[c];
    float shift = sc[32 + c];
    const float* hp = h + (size_t)bc * CHS + (size_t)s * (NZ * NX);
    for (int i4 = t; i4 < NZ * 24; i4 += 256) {        // 9 iters, 16B loads
      int z = i4 / 24, xf = i4 % 24;
      float4 v4 = *(const float4*)(hp + z * NX + xf * 4);
      float vv[4] = {v4.x, v4.y, v4.z, v4.w};
      float* dst = sh_h + z * 97 + xf * 4;
      #pragma unroll
      for (int e = 0; e < 4; ++e) {
        float v = vv[e] * scale + shift;
        dst[e] = v >= 0.f ? v : v * 0.1f;
      }
    }
  } else {
    // layer 0: expand fc0 on the fly from xin (no BN, no leaky)
    float w0 = fc0w[c], w1v = fc0w[C_ + c], bb = fc0b[c];
    const float4* xp4 = (const float4*)((const float2*)xin + ((size_t)b * NS + s) * (NZ * NX));
    for (int i4 = t; i4 < NZ * 48; i4 += 256) {        // 18 iters, 16B = 2 pts
      int z = i4 / 48, xx = (i4 % 48) * 2;
      float4 v = xp4[i4];
      float* dst = sh_h + z * 97 + xx;
      dst[0] = v.x * w0 + v.y * w1v + bb;
      dst[1] = v.z * w0 + v.w * w1v + bb;
    }
  }
  __syncthreads();
  // dftx: waves 0-1 -> kx 0..5, waves 2-3 -> kx 6..11; z = t&127 (<96 active)
  {
    int half = __builtin_amdgcn_readfirstlane(t >> 7);   // wave-uniform
    int z = t & 127;
    if (z < 96) {
      float ar[6], ai[6];
      #pragma unroll
      for (int j = 0; j < 6; ++j) { ar[j] = 0.f; ai[j] = 0.f; }
      const float2* twx = twxf + half * 6;
      const float* row = sh_h + z * 97;
      for (int x = 0; x < 96; ++x) {
        float v = row[x];              // 1 ds_read per 12 FMAs
        #pragma unroll
        for (int j = 0; j < 6; ++j) {
          float2 w = twx[x * 12 + j];  // wave-uniform -> s_load (K$-hot)
          ar[j] += v * w.x; ai[j] += v * w.y;
        }
      }
      #pragma unroll
      for (int j = 0; j < 6; ++j)
        sh_fx[z * 12 + half * 6 + j] = make_float2(ar[j], ai[j]);
    }
  }
  __syncthreads();
  // dftz: item = (kz,kx), 288 items; dual accumulators, tw L1-hot vector loads
  float2* outp = fzx + (size_t)bcs * 288;
  for (int it = t; it < 288; it += 256) {
    int kx = it % 12, kz = it / 12;
    float ar0 = 0.f, ai0 = 0.f, ar1 = 0.f, ai1 = 0.f;
    for (int z = 0; z < 96; z += 2) {
      float2 v0 = sh_fx[z * 12 + kx];
      float2 w0 = twzf[z * 24 + kz];
      float2 v1 = sh_fx[(z + 1) * 12 + kx];
      float2 w1 = twzf[(z + 1) * 24 + kz];
      ar0 += v0.x * w0.x - v0.y * w0.y;
      ai0 += v0.x * w0.y + v0.y * w0.x;
      ar1 += v1.x * w1.x - v1.y * w1.y;
      ai1 += v1.x * w1.y + v1.y * w1.x;
    }
    outp[it] = make_float2(ar0 + ar1, ai0 + ai1);   // coalesced
  }
}

// Fs[bc][ks*288+kzkx] = sum_s Fzx[bc][s][kzkx] * tw; thread per output.
__global__ __launch_bounds__(256) void k_dfts(const float2* __restrict__ fzx, float2* __restrict__ fs,
                       const float2* __restrict__ tw) {
  int tid = blockIdx.x * 256 + threadIdx.x;   // 294,912
  int kzkx = tid % 288;
  int ks = (tid / 288) & 15;
  int bc = tid / 4608;
  const float2* src = fzx + (size_t)bc * (32 * 288) + kzkx;
  float ar = 0.f, ai = 0.f;
  #pragma unroll 8
  for (int s = 0; s < 32; ++s) {
    float2 v = src[s * 288];
    float2 w = tw[s * 16 + ks];
    ar += v.x * w.x - v.y * w.y;
    ai += v.x * w.y + v.y * w.x;
  }
  fs[(size_t)bc * 4608 + ks * 288 + kzkx] = make_float2(ar, ai);
}

// G[b][o][fidx] = sum_i Fs[b][i][fidx] * w[l,q,i,o,mode]; lanes = consecutive modes
__global__ __launch_bounds__(256) void k_mix(const float2* __restrict__ fs, const float* __restrict__ spec,
                      int l, float2* __restrict__ g) {
  int tid = blockIdx.x * 256 + threadIdx.x;   // 147,456 = 4q * 32o * 1152m
  int m = tid % 1152;
  int o = (tid / 1152) & 31;
  int q = tid / 36864;
  int m1 = m / 144, r = m - m1 * 144, m2 = r / 12, m3 = r - m2 * 12;
  int ks = m1 + (q & 1) * 8;
  int kz = m2 + ((q >> 1) & 1) * 12;
  int fidx = (ks * KZ + kz) * KX + m3;
  const float2* w2 = (const float2*)spec;
  size_t widx = ((size_t)(l * 4 + q) * 1024 + o) * 1152 + m;   // + i*36864 per i
  const float2* f0 = fs + fidx;                                 // + i*4608 per i
  const float2* f1 = fs + (size_t)C_ * 4608 + fidx;
  float a0r = 0.f, a0i = 0.f, a1r = 0.f, a1i = 0.f;
  #pragma unroll 4
  for (int i = 0; i < C_; ++i) {
    float2 w = w2[widx];  widx += 36864;
    float2 v0 = f0[(size_t)i * 4608];
    float2 v1 = f1[(size_t)i * 4608];
    a0r += v0.x * w.x - v0.y * w.y;  a0i += v0.x * w.y + v0.y * w.x;
    a1r += v1.x * w.x - v1.y * w.y;  a1i += v1.x * w.y + v1.y * w.x;
  }
  g[(size_t)o * 4608 + fidx] = make_float2(a0r, a0i);
  g[(size_t)(C_ + o) * 4608 + fidx] = make_float2(a1r, a1i);
}

// Fused idfts+idftz. block = (bo, s): stage g[bo] (36.9 KB) in LDS, compute
// gs slice [288] in LDS (16-term s-inverse, twiddles via s_load since s is
// block-uniform), then gz row [z=96][kx=12] (24-term z-inverse, twzi L1-hot).
// r12: float4 staging of sh_g (9 iters of 16B loads vs 18 of 8B).
__global__ __launch_bounds__(256) void k_idft_sz(const float2* __restrict__ g, float2* __restrict__ gz,
                        const float2* __restrict__ twsi, const float2* __restrict__ twzi) {
  __shared__ float2 sh_g[4608];    // 36.9 KB, this bo's full G
  __shared__ float2 sh_gs[288];    // 2.3 KB, gs slice for this s
  int t = threadIdx.x;
  int bo = blockIdx.x >> 5;
  int s  = blockIdx.x & 31;
  const float4* gsrc4 = (const float4*)(g + (size_t)bo * 4608);
  float4* shg4 = (float4*)sh_g;
  for (int i = t; i < 2304; i += 256) shg4[i] = gsrc4[i];   // coalesced, L2-hot
  __syncthreads();
  // gs[kzkx] = sum_ks sh_g[ks*288+kzkx] * twsi[ks*32+s]  (twsi: s_load)
  for (int it = t; it < 288; it += 256) {
    float ar = 0.f, ai = 0.f;
    #pragma unroll
    for (int ks = 0; ks < 16; ++ks) {
      float2 v = sh_g[ks * 288 + it];
      float2 w = twsi[ks * 32 + s];
      ar += v.x * w.x - v.y * w.y;
      ai += v.x * w.y + v.y * w.x;
    }
    sh_gs[it] = make_float2(ar, ai);
  }
  __syncthreads();
  // gz[z][kx] = sum_kz sh_gs[kz*12+kx] * twzi[kz*96+z]
  float2* outp = gz + (size_t)(bo * 32 + s) * 1152;
  for (int it = t; it < 1152; it += 256) {
    int kx = it % 12, z = it / 12;
    float ar = 0.f, ai = 0.f;
    #pragma unroll 8
    for (int kz = 0; kz < 24; ++kz) {
      float2 v = sh_gs[kz * 12 + kx];
      float2 w = twzi[kz * 96 + z];
      ar += v.x * w.x - v.y * w.y;
      ai += v.x * w.y + v.y * w.x;
    }
    outp[it] = make_float2(ar, ai);    // coalesced
  }
}

// a[b][o][s][z][x] = Re(sum_kx Gz e^{+..}) + sum_i ww[o][i] h_bn[b][i][s][z][x] + wb[o]
// r11 form (kept): transposed [x][c] h tile stride 34, float4 h staging,
// float4 gz staging; FETCH 55->21 MB, VALU 65%, occ 59%. Stuck at ~89us over
// 3 structural attempts -> pinned by issue/latency structure; deprioritized.
__global__ __launch_bounds__(256) void k_idftx_fuse(const float2* __restrict__ gz, const float* __restrict__ hsrc,
                             const float* __restrict__ xin, const float* __restrict__ fc0w,
                             const float* __restrict__ fc0b,
                             const float* __restrict__ ww, const float* __restrict__ wb,
                             const float2* __restrict__ twxi, const float* __restrict__ sc,
                             int use_bn, float* __restrict__ adst, float* __restrict__ stp) {
  __shared__ float  sh_ht[NX * 34];   // 12.75 KB, transposed [x][c]; later [x][o] scratch
  __shared__ float2 sh_g[C_ * KX];    // 3 KB, this (b,s,z)'s 32x12 gz fragments
  int blk = blockIdx.x;               // z fastest
  int z = blk % NZ, s = (blk / NZ) % NS, b = blk / (NZ * NS);
  int t = threadIdx.x;
  size_t rowbase = ((size_t)b * C_) * CHS + (size_t)s * (NZ * NX) + (size_t)z * NX;
  if (use_bn) {
    // float4 staging: 768 items = 32 c x 24 float4-per-row
    for (int i4 = t; i4 < C_ * 24; i4 += 256) {
      int c = i4 / 24, xf = i4 % 24;
      float4 v4 = *(const float4*)(hsrc + rowbase + (size_t)c * CHS + xf * 4);
      float scl = sc[c], shf = sc[32 + c];
      float vv[4] = {v4.x, v4.y, v4.z, v4.w};
      #pragma unroll
      for (int e = 0; e < 4; ++e) {
        float v = vv[e] * scl + shf;
        v = v >= 0.f ? v : v * 0.1f;
        sh_ht[(xf * 4 + e) * 34 + c] = v;
      }
    }
  } else {
    // layer 0: expand fc0 from xin row (no BN, no leaky); transposed write
    const float2* xp = (const float2*)xin + (((size_t)b * NS + s) * NZ + z) * NX;
    for (int i = t; i < C_ * NX; i += 256) {
      int c = i / NX, x = i % NX;
      float2 xv = xp[x];               // L1-hot (row re-read across c)
      sh_ht[x * 34 + c] = xv.x * fc0w[c] + xv.y * fc0w[C_ + c] + fc0b[c];
    }
  }
  // stage gz as float4: 192 loads (o = t/6, f = t%6); 96B rows, 16B-aligned
  if (t < 192) {
    int o = t / 6, f = t % 6;
    const float4* gp = (const float4*)(gz + (((size_t)(b * C_ + o) * NS + s) * NZ + z) * KX);
    ((float4*)sh_g)[o * 6 + f] = gp[f];
  }
  __syncthreads();
  int x = t & 127;
  int og = __builtin_amdgcn_readfirstlane(t >> 7);   // wave-uniform
  float acc[16];
  if (x < NX) {
    float2 tw[KX];
    #pragma unroll
    for (int k = 0; k < KX; ++k) tw[k] = twxi[k * NX + x];
    #pragma unroll
    for (int j = 0; j < 16; ++j) {
      int o = og * 16 + j;
      float a = wb[o];                                  // s_load
      const float2* gp = sh_g + o * KX;                 // LDS broadcast (free)
      #pragma unroll
      for (int k = 0; k < KX; ++k) {
        float2 gv = gp[k];
        a += gv.x * tw[k].x - gv.y * tw[k].y;
      }
      acc[j] = a;
    }
    const float* wwb = ww + og * 16 * C_;
    #pragma unroll 4
    for (int i2 = 0; i2 < 16; ++i2) {
      float2 hv = *(const float2*)(sh_ht + x * 34 + 2 * i2);  // ds_read_b64
      #pragma unroll
      for (int j = 0; j < 16; ++j) acc[j] += wwb[j * C_ + 2 * i2] * hv.x;     // s_load
      #pragma unroll
      for (int j = 0; j < 16; ++j) acc[j] += wwb[j * C_ + 2 * i2 + 1] * hv.y; // s_load
    }
    #pragma unroll
    for (int j = 0; j < 16; ++j)
      adst[rowbase + (size_t)(og * 16 + j) * CHS + x] = acc[j];
  }
  // ---- fused BN stats: reduce raw acc over this block's 96 x per channel ----
  __syncthreads();                    // everyone done reading sh_ht
  if (x < NX) {
    #pragma unroll
    for (int j = 0; j < 16; ++j) sh_ht[x * 34 + og * 16 + j] = acc[j];
  }
  __syncthreads();
  {
    int o = t >> 3, ch = t & 7;       // 32 channels x 8 chunks of 12
    float s1 = 0.f, s2 = 0.f;
    #pragma unroll
    for (int k = 0; k < 12; ++k) {
      float v = sh_ht[(ch * 12 + k) * 34 + o];
      s1 += v; s2 += v * v;
    }
    s1 += __shfl_down(s1, 4);  s2 += __shfl_down(s2, 4);
    s1 += __shfl_down(s1, 2);  s2 += __shfl_down(s2, 2);
    s1 += __shfl_down(s1, 1);  s2 += __shfl_down(s2, 1);
    if (ch == 0) {
      float* slot = stp + (size_t)(blk & 63) * 64;     // hashed partial copy
      atomicAdd(&slot[o], s1);
      atomicAdd(&slot[32 + o], s2);
    }
  }
}

// reduce 64 partial slots -> (scale, shift) for this layer
__global__ void k_bnfinal(const float* __restrict__ stp, const float* __restrict__ g,
                          const float* __restrict__ bb, float* __restrict__ sc) {
  __shared__ float tot[64];
  int t = threadIdx.x;                // 64 threads
  float s = 0.f;
  for (int slot = 0; slot < 64; ++slot) s += stp[slot * 64 + t];
  tot[t] = s;
  __syncthreads();
  if (t < 32) {
    const float N = (float)NPTS;
    float mean = tot[t] / N;
    float var = tot[32 + t] / N - mean * mean;
    float inv = rsqrtf(var + 1e-5f);
    float scale = inv * g[t];
    sc[t] = scale;
    sc[32 + t] = bb[t] - mean * scale;
  }
}

// MLP, LDS-activation + scalar-weight design, 512-thread blocks (8 waves).
// r9 scalar form (r10's float2 LDS reads were neutral-to-negative -> the
// residual is NOT LDS-issue-bound; reverted). Measured: 256thr=492us,
// 1024thr=593us, 512thr=380us. 8 sub-launches for rocprof visibility.
__global__ __launch_bounds__(512, 6) void k_mlp(
    const float* __restrict__ h, const float* __restrict__ xin,
    const float* __restrict__ sc, int blk0,
    const float* __restrict__ w1, const float* __restrict__ b1,
    const float* __restrict__ w2, const float* __restrict__ b2,
    const float* __restrict__ w3, const float* __restrict__ b3,
    const float* __restrict__ w4, const float* __restrict__ b4,
    const float* __restrict__ w5, const float* __restrict__ b5,
    const float* __restrict__ w7, const float* __restrict__ b7,
    float* __restrict__ out) {
  __shared__ float A[64 * 65];    // 16.6 KB (32/64-wide activations)
  __shared__ float Bf[64 * 129];  // 33 KB  (128/32-wide activations)
  __shared__ float P[64 * 9];     // 2.3 KB (fc7 per-wave partials)
  int t = threadIdx.x;
  int p = t & 63;                                      // point within block
  int q = __builtin_amdgcn_readfirstlane(t >> 6);      // wave id 0..7, uniform
  int pt0 = (blockIdx.x + blk0) * 64;

  // phase 0: A[p][c] = leaky(BN3(h)); lanes -> consecutive points (coalesced)
  for (int i = t; i < 64 * 32; i += 512) {
    int c = i >> 6, pp = i & 63;
    int pt = pt0 + pp;
    size_t base = (size_t)(pt / CHS) * C_ * CHS + (pt % CHS);
    float v = h[base + (size_t)c * CHS];
    v = v * sc[c] + sc[32 + c];                        // sc via s_load
    A[pp * 65 + c] = v >= 0.f ? v : 0.1f * v;
  }
  __syncthreads();

  // phase 1: fc1 (32->128): A -> Bf, 16 outputs/thread (m0 = q*16)
  {
    const int m0 = q * 16;
    float acc[16];
    #pragma unroll
    for (int j = 0; j < 16; ++j) acc[j] = b1[m0 + j];
    const float* arow = A + p * 65;
    #pragma unroll 4
    for (int k = 0; k < 32; ++k) {
      float a = arow[k];
      const float* wr = w1 + k * 128 + m0;             // uniform -> s_load
      #pragma unroll
      for (int j = 0; j < 16; ++j) acc[j] += a * wr[j];
    }
    float* brow = Bf + p * 129 + m0;
    #pragma unroll
    for (int j = 0; j < 16; ++j) {
      float v = acc[j];
      brow[j] = v >= 0.f ? v : 0.1f * v;
    }
  }
  __syncthreads();

  // phase 2: fc2 (128->64): Bf -> A, 8 outputs/thread (m0 = q*8)
  {
    const int m0 = q * 8;
    float acc[8];
    #pragma unroll
    for (int j = 0; j < 8; ++j) acc[j] = b2[m0 + j];
    const float* brow = Bf + p * 129;
    #pragma unroll 4
    for (int k = 0; k < 128; ++k) {
      float a = brow[k];
      const float* wr = w2 + k * 64 + m0;              // s_load
      #pragma unroll
      for (int j = 0; j < 8; ++j) acc[j] += a * wr[j];
    }
    float* arow = A + p * 65 + m0;
    #pragma unroll
    for (int j = 0; j < 8; ++j) {
      float v = acc[j];
      arow[j] = v >= 0.f ? v : 0.1f * v;
    }
  }
  __syncthreads();

  // phase 3: fc3 (64->32): A -> Bf (low cols), 4 outputs/thread (m0 = q*4)
  {
    const int m0 = q * 4;
    float acc[4];
    #pragma unroll
    for (int j = 0; j < 4; ++j) acc[j] = b3[m0 + j];
    const float* arow = A + p * 65;
    #pragma unroll 4
    for (int k = 0; k < 64; ++k) {
      float a = arow[k];
      const float* wr = w3 + k * 32 + m0;              // s_load
      #pragma unroll
      for (int j = 0; j < 4; ++j) acc[j] += a * wr[j];
    }
    float* brow = Bf + p * 129 + m0;
    #pragma unroll
    for (int j = 0; j < 4; ++j) {
      float v = acc[j];
      brow[j] = v >= 0.f ? v : 0.1f * v;
    }
  }
  __syncthreads();

  // phase 4: fc4 (32->64): Bf -> A, 8 outputs/thread (m0 = q*8)
  {
    const int m0 = q * 8;
    float acc[8];
    #pragma unroll
    for (int j = 0; j < 8; ++j) acc[j] = b4[m0 + j];
    const float* brow = Bf + p * 129;
    #pragma unroll 4
    for (int k = 0; k < 32; ++k) {
      float a = brow[k];
      const float* wr = w4 + k * 64 + m0;              // s_load
      #pragma unroll
      for (int j = 0; j < 8; ++j) acc[j] += a * wr[j];
    }
    float* arow = A + p * 65 + m0;
    #pragma unroll
    for (int j = 0; j < 8; ++j) {
      float v = acc[j];
      arow[j] = v >= 0.f ? v : 0.1f * v;
    }
  }
  __syncthreads();

  // phase 5: fc5 (64->128) fused with fc7 (128->1): per-wave partial dot
  {
    const int m0 = q * 16;
    float acc[16];
    #pragma unroll
    for (int j = 0; j < 16; ++j) acc[j] = b5[m0 + j];
    const float* arow = A + p * 65;
    #pragma unroll 4
    for (int k = 0; k < 64; ++k) {
      float a = arow[k];
      const float* wr = w5 + k * 128 + m0;             // s_load
      #pragma unroll
      for (int j = 0; j < 16; ++j) acc[j] += a * wr[j];
    }
    float partial = 0.f;
    #pragma unroll
    for (int j = 0; j < 16; ++j) {
      float v = acc[j];
      v = v >= 0.f ? v : 0.1f * v;                     // leaky(fc5)
      partial += v * w7[m0 + j];                       // s_load
    }
    P[p * 9 + q] = partial;
  }
  __syncthreads();

  // phase 6: wave 0 reduces the 8 partials, applies mask, stores
  if (q == 0) {
    int pt = pt0 + p;
    float acc = b7[0];
    #pragma unroll
    for (int j = 0; j < 8; ++j) acc += P[p * 9 + j];
    float T0 = xin[2 * pt + 1];
    float mask = (T0 < 0.01f) ? T0 : 1.0f;
    int z = (pt / NX) % NZ;
    if (z < 2) mask = 0.f;
    out[pt] = acc * mask;
  }
}

__global__ void k_loss(const float* __restrict__ tau, const float* __restrict__ xin,
                       const float* __restrict__ y, float* __restrict__ loss) {
  int pt = blockIdx.x * 256 + threadIdx.x;
  int x = pt % NX, z = (pt / NX) % NZ;
  float tpx = (x < NX - 1) ? tau[pt + 1] : 0.f;
  float tmx = (x > 0) ? tau[pt - 1] : 0.f;
  float tpz = (z < NZ - 1) ? tau[pt + NX] : 0.f;
  float tmz = (z > 0) ? tau[pt - NX] : 0.f;
  float Tpx = (x < NX - 1) ? xin[2 * (pt + 1) + 1] : 0.f;
  float Tmx = (x > 0) ? xin[2 * (pt - 1) + 1] : 0.f;
  float Tpz = (z < NZ - 1) ? xin[2 * (pt + NX) + 1] : 0.f;
  float Tmz = (z > 0) ? xin[2 * (pt - NX) + 1] : 0.f;
  float dx = (tpx - tmx) * 50.f + (Tpx - Tmx) * 50.f;
  float dz = (tpz - tmz) * 50.f + (Tpz - Tmz) * 50.f;
  loss[pt] = dx * dx + dz * dz - y[pt];
}

extern "C" void kernel_launch(void* const* d_in, const int* in_sizes, int n_in,
                              void* d_out, int out_size, void* d_ws, size_t ws_size,
                              hipStream_t stream) {
  (void)in_sizes; (void)n_in; (void)out_size; (void)ws_size;
  const float* xin    = (const float*)d_in[0];
  const float* y      = (const float*)d_in[1];
  const float* fc0_w  = (const float*)d_in[2];
  const float* fc0_b  = (const float*)d_in[3];
  const float* spec_w = (const float*)d_in[4];
  const float* w_w    = (const float*)d_in[5];
  const float* w_b    = (const float*)d_in[6];
  const float* bn_g   = (const float*)d_in[7];
  const float* bn_b   = (const float*)d_in[8];
  const float* fc1_w  = (const float*)d_in[9];
  const float* fc1_b  = (const float*)d_in[10];
  const float* fc2_w  = (const float*)d_in[11];
  const float* fc2_b  = (const float*)d_in[12];
  const float* fc3_w  = (const float*)d_in[13];
  const float* fc3_b  = (const float*)d_in[14];
  const float* fc4_w  = (const float*)d_in[15];
  const float* fc4_b  = (const float*)d_in[16];
  const float* fc5_w  = (const float*)d_in[17];
  const float* fc5_b  = (const float*)d_in[18];
  const float* fc7_w  = (const float*)d_in[19];
  const float* fc7_b  = (const float*)d_in[20];
  float* ws  = (float*)d_ws;
  float* out = (float*)d_out;

  k_init_tw<<<1, 256, 0, stream>>>(ws);
  k_zero_stats<<<64, 256, 0, stream>>>(ws + OFF_STP);
  // NOTE: no k_fc0 -- layer 0 expands fc0 on the fly in k_fwd/k_idftx_fuse.

  float* hsrc = ws + OFF_HA;   // unwritten for l=0; layer-0 kernels don't read it
  float* hdst = ws + OFF_HB;
  for (int l = 0; l < 4; ++l) {
    const float* sc_prev = ws + OFF_SC + (size_t)(l - 1) * 64;  // only read if l>0
    int use_bn = (l > 0) ? 1 : 0;
    float* stp_l = ws + OFF_STP + (size_t)l * 4096;
    k_fwd<<<B_ * C_ * NS, 256, 0, stream>>>(hsrc, xin, fc0_w, fc0_b,
                                            (float2*)(ws + OFF_FZX),
                                            (const float2*)(ws + OFF_TWXF),
                                            (const float2*)(ws + OFF_TWZF), sc_prev, use_bn);
    k_dfts<<<1152, 256, 0, stream>>>((const float2*)(ws + OFF_FZX), (float2*)(ws + OFF_FS),
                                     (const float2*)(ws + OFF_TWSF));
    k_mix<<<576, 256, 0, stream>>>((const float2*)(ws + OFF_FS), spec_w, l,
                                   (float2*)(ws + OFF_G));
    k_idft_sz<<<64 * 32, 256, 0, stream>>>((const float2*)(ws + OFF_G), (float2*)(ws + OFF_FX),
                                           (const float2*)(ws + OFF_TWSI),
                                           (const float2*)(ws + OFF_TWZI));
    k_idftx_fuse<<<B_ * NS * NZ, 256, 0, stream>>>((const float2*)(ws + OFF_FX), hsrc,
                                                   xin, fc0_w, fc0_b,
                                                   w_w + (size_t)l * C_ * C_, w_b + (size_t)l * C_,
                                                   (const float2*)(ws + OFF_TWXI), sc_prev,
                                                   use_bn, hdst, stp_l);
    k_bnfinal<<<1, 64, 0, stream>>>(stp_l, bn_g + (size_t)l * C_,
                                    bn_b + (size_t)l * C_, ws + OFF_SC + (size_t)l * 64);
    float* tmp = hsrc; hsrc = hdst; hdst = tmp;
  }

  // 8 sub-launches of 1152 blocks: keeps per-dispatch dur small so spectral
  // kernels stay visible in the rocprof top-5 (diagnostic; ~15us cost)
  for (int part = 0; part < 8; ++part) {
    k_mlp<<<1152, 512, 0, stream>>>(hsrc, xin, ws + OFF_SC + 192, part * 1152,
                                    fc1_w, fc1_b, fc2_w, fc2_b, fc3_w, fc3_b,
                                    fc4_w, fc4_b, fc5_w, fc5_b, fc7_w, fc7_b, out);
  }
  k_loss<<<NPTS / 256, 256, 0, stream>>>(out, xin, y, out + NPTS);
}

// Round 13
// 1288.903 us; speedup vs baseline: 1.0998x; 1.0592x over previous
//
#include <hip/hip_runtime.h>
#include <math.h>

constexpr int B_ = 2, C_ = 32, NS = 32, NZ = 96, NX = 96;
constexpr int KS = 16, KZ = 24, KX = 12;          // kept mode counts (s, z, x)
constexpr int NPTS = B_ * NS * NZ * NX;           // 589824
constexpr int CHS  = NS * NZ * NX;                // 294912 (per-channel stride)
constexpr size_t HSIZE = (size_t)B_ * C_ * CHS;   // 18,874,368 floats

constexpr size_t FX_C  = (size_t)B_ * C_ * NS * KX * NZ;  // 2,359,296 cplx (gz)
constexpr size_t FZX_C = (size_t)B_ * C_ * KZ * KX * NS;  //   589,824 cplx (fzx)
constexpr size_t FS_C  = (size_t)B_ * C_ * KS * KZ * KX;  //   294,912 cplx

// workspace offsets (floats). gz overlays FX.
constexpr size_t OFF_HA   = 0;
constexpr size_t OFF_HB   = OFF_HA + HSIZE;
constexpr size_t OFF_FX   = OFF_HB + HSIZE;
constexpr size_t OFF_FZX  = OFF_FX + 2 * FX_C;
constexpr size_t OFF_FS   = OFF_FZX + 2 * FZX_C;
constexpr size_t OFF_G    = OFF_FS + 2 * FS_C;
constexpr size_t OFF_ST   = OFF_G + 2 * FS_C;     // (legacy, unused)
constexpr size_t OFF_SC   = OFF_ST + 256;         // 4 layers x (scale[32], shift[32])
constexpr size_t OFF_TWXF = OFF_SC + 256;         // [x=96][k=12] cplx, e^{-i}
constexpr size_t OFF_TWZF = OFF_TWXF + 2 * 96 * 12;   // [z=96][k=24]
constexpr size_t OFF_TWSF = OFF_TWZF + 2 * 96 * 24;   // [s=32][k=16], includes 1/294912
constexpr size_t OFF_TWSI = OFF_TWSF + 2 * 32 * 16;   // [k=16][s=32] cplx, e^{+i}
constexpr size_t OFF_TWZI = OFF_TWSI + 2 * 16 * 32;   // [k=24][z=96]
constexpr size_t OFF_TWXI = OFF_TWZI + 2 * 24 * 96;   // [k=12][x=96]
// BN-stat PARTIALS: 4 layers x 64 slots x (sum[32],sumsq[32]) = 16384 floats.
// Hashed by (blockIdx & 63) (r6 post-mortem: single-copy same-address atomics
// from 6144 blocks serialized in L2 -> 331us; hashing fixed it to 90us, r7).
constexpr size_t OFF_STP  = OFF_TWXI + 2 * 12 * 96;

__global__ void k_init_tw(float* ws) {
  const double TWO_PI = 6.283185307179586476925286766559;
  int t = threadIdx.x;
  float2* twxf = (float2*)(ws + OFF_TWXF);
  for (int i = t; i < 96 * 12; i += 256) {
    int x = i / 12, k = i % 12;
    double a = -TWO_PI * (double)((k * x) % 96) / 96.0;
    twxf[i] = make_float2((float)cos(a), (float)sin(a));
  }
  float2* twzf = (float2*)(ws + OFF_TWZF);
  for (int i = t; i < 96 * 24; i += 256) {
    int z = i / 24, k = i % 24;
    double a = -TWO_PI * (double)((k * z) % 96) / 96.0;
    twzf[i] = make_float2((float)cos(a), (float)sin(a));
  }
  float2* twsf = (float2*)(ws + OFF_TWSF);
  const double SC = 1.0 / (double)(NS * NZ * NX);  // fftn norm='forward'
  for (int i = t; i < 32 * 16; i += 256) {
    int s = i / 16, k = i % 16;
    int f = (k < 8) ? k : k + 16;                  // s-modes 0..7, 24..31
    double a = -TWO_PI * (double)((f * s) % 32) / 32.0;
    twsf[i] = make_float2((float)(cos(a) * SC), (float)(sin(a) * SC));
  }
  float2* twsi = (float2*)(ws + OFF_TWSI);
  for (int i = t; i < 16 * 32; i += 256) {
    int k = i / 32, s = i % 32;
    int f = (k < 8) ? k : k + 16;
    double a = TWO_PI * (double)((f * s) % 32) / 32.0;
    twsi[i] = make_float2((float)cos(a), (float)sin(a));
  }
  float2* twzi = (float2*)(ws + OFF_TWZI);
  for (int i = t; i < 24 * 96; i += 256) {
    int k = i / 96, z = i % 96;
    int f = (k < 12) ? k : k + 72;                 // z-modes 0..11, 84..95
    double a = TWO_PI * (double)((f * z) % 96) / 96.0;
    twzi[i] = make_float2((float)cos(a), (float)sin(a));
  }
  float2* twxi = (float2*)(ws + OFF_TWXI);
  for (int i = t; i < 12 * 96; i += 256) {
    int k = i / 96, x = i % 96;
    double a = TWO_PI * (double)((k * x) % 96) / 96.0;
    twxi[i] = make_float2((float)cos(a), (float)sin(a));
  }
}

__global__ void k_zero_stats(float* stp) {
  stp[blockIdx.x * 256 + threadIdx.x] = 0.f;   // 64 blocks x 256 = 16384 floats
}

// Fused dftx+dftz. block = (b,c,s). Stage BN(h) plane in LDS (coalesced, +97
// pad), dftx with 6 complex reg-accumulators per thread + SCALAR twiddles
// (half = t>>7 is wave-uniform), dftz with dual accumulators.
// r12: float4 global staging (r11 pattern). LDS writes stay scalar to
// preserve the conflict-free stride-97 rows. Layer 0 (use_bn==0): h never
// materialized -- expand fc0 from the xin slab (L2-resident).
__global__ __launch_bounds__(256) void k_fwd(const float* __restrict__ h, const float* __restrict__ xin,
                      const float* __restrict__ fc0w, const float* __restrict__ fc0b,
                      float2* __restrict__ fzx,
                      const float2* __restrict__ twxf, const float2* __restrict__ twzf,
                      const float* __restrict__ sc, int use_bn) {
  __shared__ float  sh_h[96 * 97];     // 37.2 KB
  __shared__ float2 sh_fx[96 * 12];    // 9 KB  [z][kx]
  int t = threadIdx.x;
  int bcs = blockIdx.x;               // 2048 = 64 bc * 32 s
  int s = bcs & 31;
  int bc = bcs >> 5;
  int c = bc & 31;
  int b = bc >> 5;
  if (use_bn) {
    float scale = sc[c];
    float shift = sc[32 + c];
    const float* hp = h + (size_t)bc * CHS + (size_t)s * (NZ * NX);
    for (int i4 = t; i4 < NZ * 24; i4 += 256) {        // 9 iters, 16B loads
      int z = i4 / 24, xf = i4 % 24;
      float4 v4 = *(const float4*)(hp + z * NX + xf * 4);
      float vv[4] = {v4.x, v4.y, v4.z, v4.w};
      float* dst = sh_h + z * 97 + xf * 4;
      #pragma unroll
      for (int e = 0; e < 4; ++e) {
        float v = vv[e] * scale + shift;
        dst[e] = v >= 0.f ? v : v * 0.1f;
      }
    }
  } else {
    // layer 0: expand fc0 on the fly from xin (no BN, no leaky)
    float w0 = fc0w[c], w1v = fc0w[C_ + c], bb = fc0b[c];
    const float4* xp4 = (const float4*)((const float2*)xin + ((size_t)b * NS + s) * (NZ * NX));
    for (int i4 = t; i4 < NZ * 48; i4 += 256) {        // 18 iters, 16B = 2 pts
      int z = i4 / 48, xx = (i4 % 48) * 2;
      float4 v = xp4[i4];
      float* dst = sh_h + z * 97 + xx;
      dst[0] = v.x * w0 + v.y * w1v + bb;
      dst[1] = v.z * w0 + v.w * w1v + bb;
    }
  }
  __syncthreads();
  // dftx: waves 0-1 -> kx 0..5, waves 2-3 -> kx 6..11; z = t&127 (<96 active)
  {
    int half = __builtin_amdgcn_readfirstlane(t >> 7);   // wave-uniform
    int z = t & 127;
    if (z < 96) {
      float ar[6], ai[6];
      #pragma unroll
      for (int j = 0; j < 6; ++j) { ar[j] = 0.f; ai[j] = 0.f; }
      const float2* twx = twxf + half * 6;
      const float* row = sh_h + z * 97;
      for (int x = 0; x < 96; ++x) {
        float v = row[x];              // 1 ds_read per 12 FMAs
        #pragma unroll
        for (int j = 0; j < 6; ++j) {
          float2 w = twx[x * 12 + j];  // wave-uniform -> s_load (K$-hot)
          ar[j] += v * w.x; ai[j] += v * w.y;
        }
      }
      #pragma unroll
      for (int j = 0; j < 6; ++j)
        sh_fx[z * 12 + half * 6 + j] = make_float2(ar[j], ai[j]);
    }
  }
  __syncthreads();
  // dftz: item = (kz,kx), 288 items; dual accumulators, tw L1-hot vector loads
  float2* outp = fzx + (size_t)bcs * 288;
  for (int it = t; it < 288; it += 256) {
    int kx = it % 12, kz = it / 12;
    float ar0 = 0.f, ai0 = 0.f, ar1 = 0.f, ai1 = 0.f;
    for (int z = 0; z < 96; z += 2) {
      float2 v0 = sh_fx[z * 12 + kx];
      float2 w0 = twzf[z * 24 + kz];
      float2 v1 = sh_fx[(z + 1) * 12 + kx];
      float2 w1 = twzf[(z + 1) * 24 + kz];
      ar0 += v0.x * w0.x - v0.y * w0.y;
      ai0 += v0.x * w0.y + v0.y * w0.x;
      ar1 += v1.x * w1.x - v1.y * w1.y;
      ai1 += v1.x * w1.y + v1.y * w1.x;
    }
    outp[it] = make_float2(ar0 + ar1, ai0 + ai1);   // coalesced
  }
}

// Fs[bc][ks*288+kzkx] = sum_s Fzx[bc][s][kzkx] * tw; thread per output.
__global__ __launch_bounds__(256) void k_dfts(const float2* __restrict__ fzx, float2* __restrict__ fs,
                       const float2* __restrict__ tw) {
  int tid = blockIdx.x * 256 + threadIdx.x;   // 294,912
  int kzkx = tid % 288;
  int ks = (tid / 288) & 15;
  int bc = tid / 4608;
  const float2* src = fzx + (size_t)bc * (32 * 288) + kzkx;
  float ar = 0.f, ai = 0.f;
  #pragma unroll 8
  for (int s = 0; s < 32; ++s) {
    float2 v = src[s * 288];
    float2 w = tw[s * 16 + ks];
    ar += v.x * w.x - v.y * w.y;
    ai += v.x * w.y + v.y * w.x;
  }
  fs[(size_t)bc * 4608 + ks * 288 + kzkx] = make_float2(ar, ai);
}

// G[b][o][fidx] = sum_i Fs[b][i][fidx] * w[l,q,i,o,mode]; lanes = consecutive modes
__global__ __launch_bounds__(256) void k_mix(const float2* __restrict__ fs, const float* __restrict__ spec,
                      int l, float2* __restrict__ g) {
  int tid = blockIdx.x * 256 + threadIdx.x;   // 147,456 = 4q * 32o * 1152m
  int m = tid % 1152;
  int o = (tid / 1152) & 31;
  int q = tid / 36864;
  int m1 = m / 144, r = m - m1 * 144, m2 = r / 12, m3 = r - m2 * 12;
  int ks = m1 + (q & 1) * 8;
  int kz = m2 + ((q >> 1) & 1) * 12;
  int fidx = (ks * KZ + kz) * KX + m3;
  const float2* w2 = (const float2*)spec;
  size_t widx = ((size_t)(l * 4 + q) * 1024 + o) * 1152 + m;   // + i*36864 per i
  const float2* f0 = fs + fidx;                                 // + i*4608 per i
  const float2* f1 = fs + (size_t)C_ * 4608 + fidx;
  float a0r = 0.f, a0i = 0.f, a1r = 0.f, a1i = 0.f;
  #pragma unroll 4
  for (int i = 0; i < C_; ++i) {
    float2 w = w2[widx];  widx += 36864;
    float2 v0 = f0[(size_t)i * 4608];
    float2 v1 = f1[(size_t)i * 4608];
    a0r += v0.x * w.x - v0.y * w.y;  a0i += v0.x * w.y + v0.y * w.x;
    a1r += v1.x * w.x - v1.y * w.y;  a1i += v1.x * w.y + v1.y * w.x;
  }
  g[(size_t)o * 4608 + fidx] = make_float2(a0r, a0i);
  g[(size_t)(C_ + o) * 4608 + fidx] = make_float2(a1r, a1i);
}

// Fused idfts+idftz. block = (bo, s): stage g[bo] (36.9 KB) in LDS, compute
// gs slice [288] in LDS (16-term s-inverse, twiddles via s_load since s is
// block-uniform), then gz row [z=96][kx=12] (24-term z-inverse, twzi L1-hot).
// r12: float4 staging of sh_g.
__global__ __launch_bounds__(256) void k_idft_sz(const float2* __restrict__ g, float2* __restrict__ gz,
                        const float2* __restrict__ twsi, const float2* __restrict__ twzi) {
  __shared__ float2 sh_g[4608];    // 36.9 KB, this bo's full G
  __shared__ float2 sh_gs[288];    // 2.3 KB, gs slice for this s
  int t = threadIdx.x;
  int bo = blockIdx.x >> 5;
  int s  = blockIdx.x & 31;
  const float4* gsrc4 = (const float4*)(g + (size_t)bo * 4608);
  float4* shg4 = (float4*)sh_g;
  for (int i = t; i < 2304; i += 256) shg4[i] = gsrc4[i];   // coalesced, L2-hot
  __syncthreads();
  // gs[kzkx] = sum_ks sh_g[ks*288+kzkx] * twsi[ks*32+s]  (twsi: s_load)
  for (int it = t; it < 288; it += 256) {
    float ar = 0.f, ai = 0.f;
    #pragma unroll
    for (int ks = 0; ks < 16; ++ks) {
      float2 v = sh_g[ks * 288 + it];
      float2 w = twsi[ks * 32 + s];
      ar += v.x * w.x - v.y * w.y;
      ai += v.x * w.y + v.y * w.x;
    }
    sh_gs[it] = make_float2(ar, ai);
  }
  __syncthreads();
  // gz[z][kx] = sum_kz sh_gs[kz*12+kx] * twzi[kz*96+z]
  float2* outp = gz + (size_t)(bo * 32 + s) * 1152;
  for (int it = t; it < 1152; it += 256) {
    int kx = it % 12, z = it / 12;
    float ar = 0.f, ai = 0.f;
    #pragma unroll 8
    for (int kz = 0; kz < 24; ++kz) {
      float2 v = sh_gs[kz * 12 + kx];
      float2 w = twzi[kz * 96 + z];
      ar += v.x * w.x - v.y * w.y;
      ai += v.x * w.y + v.y * w.x;
    }
    outp[it] = make_float2(ar, ai);    // coalesced
  }
}

// a[b][o][s][z][x] = Re(sum_kx Gz e^{+..}) + sum_i ww[o][i] h_bn[b][i][s][z][x] + wb[o]
// r11 form (kept): transposed [x][c] h tile stride 34, float4 h staging,
// float4 gz staging; FETCH 55->21 MB, VALU 65%, occ 59%. Pinned ~89us.
__global__ __launch_bounds__(256) void k_idftx_fuse(const float2* __restrict__ gz, const float* __restrict__ hsrc,
                             const float* __restrict__ xin, const float* __restrict__ fc0w,
                             const float* __restrict__ fc0b,
                             const float* __restrict__ ww, const float* __restrict__ wb,
                             const float2* __restrict__ twxi, const float* __restrict__ sc,
                             int use_bn, float* __restrict__ adst, float* __restrict__ stp) {
  __shared__ float  sh_ht[NX * 34];   // 12.75 KB, transposed [x][c]; later [x][o] scratch
  __shared__ float2 sh_g[C_ * KX];    // 3 KB, this (b,s,z)'s 32x12 gz fragments
  int blk = blockIdx.x;               // z fastest
  int z = blk % NZ, s = (blk / NZ) % NS, b = blk / (NZ * NS);
  int t = threadIdx.x;
  size_t rowbase = ((size_t)b * C_) * CHS + (size_t)s * (NZ * NX) + (size_t)z * NX;
  if (use_bn) {
    // float4 staging: 768 items = 32 c x 24 float4-per-row
    for (int i4 = t; i4 < C_ * 24; i4 += 256) {
      int c = i4 / 24, xf = i4 % 24;
      float4 v4 = *(const float4*)(hsrc + rowbase + (size_t)c * CHS + xf * 4);
      float scl = sc[c], shf = sc[32 + c];
      float vv[4] = {v4.x, v4.y, v4.z, v4.w};
      #pragma unroll
      for (int e = 0; e < 4; ++e) {
        float v = vv[e] * scl + shf;
        v = v >= 0.f ? v : v * 0.1f;
        sh_ht[(xf * 4 + e) * 34 + c] = v;
      }
    }
  } else {
    // layer 0: expand fc0 from xin row (no BN, no leaky); transposed write
    const float2* xp = (const float2*)xin + (((size_t)b * NS + s) * NZ + z) * NX;
    for (int i = t; i < C_ * NX; i += 256) {
      int c = i / NX, x = i % NX;
      float2 xv = xp[x];               // L1-hot (row re-read across c)
      sh_ht[x * 34 + c] = xv.x * fc0w[c] + xv.y * fc0w[C_ + c] + fc0b[c];
    }
  }
  // stage gz as float4: 192 loads (o = t/6, f = t%6); 96B rows, 16B-aligned
  if (t < 192) {
    int o = t / 6, f = t % 6;
    const float4* gp = (const float4*)(gz + (((size_t)(b * C_ + o) * NS + s) * NZ + z) * KX);
    ((float4*)sh_g)[o * 6 + f] = gp[f];
  }
  __syncthreads();
  int x = t & 127;
  int og = __builtin_amdgcn_readfirstlane(t >> 7);   // wave-uniform
  float acc[16];
  if (x < NX) {
    float2 tw[KX];
    #pragma unroll
    for (int k = 0; k < KX; ++k) tw[k] = twxi[k * NX + x];
    #pragma unroll
    for (int j = 0; j < 16; ++j) {
      int o = og * 16 + j;
      float a = wb[o];                                  // s_load
      const float2* gp = sh_g + o * KX;                 // LDS broadcast (free)
      #pragma unroll
      for (int k = 0; k < KX; ++k) {
        float2 gv = gp[k];
        a += gv.x * tw[k].x - gv.y * tw[k].y;
      }
      acc[j] = a;
    }
    const float* wwb = ww + og * 16 * C_;
    #pragma unroll 4
    for (int i2 = 0; i2 < 16; ++i2) {
      float2 hv = *(const float2*)(sh_ht + x * 34 + 2 * i2);  // ds_read_b64
      #pragma unroll
      for (int j = 0; j < 16; ++j) acc[j] += wwb[j * C_ + 2 * i2] * hv.x;     // s_load
      #pragma unroll
      for (int j = 0; j < 16; ++j) acc[j] += wwb[j * C_ + 2 * i2 + 1] * hv.y; // s_load
    }
    #pragma unroll
    for (int j = 0; j < 16; ++j)
      adst[rowbase + (size_t)(og * 16 + j) * CHS + x] = acc[j];
  }
  // ---- fused BN stats: reduce raw acc over this block's 96 x per channel ----
  __syncthreads();                    // everyone done reading sh_ht
  if (x < NX) {
    #pragma unroll
    for (int j = 0; j < 16; ++j) sh_ht[x * 34 + og * 16 + j] = acc[j];
  }
  __syncthreads();
  {
    int o = t >> 3, ch = t & 7;       // 32 channels x 8 chunks of 12
    float s1 = 0.f, s2 = 0.f;
    #pragma unroll
    for (int k = 0; k < 12; ++k) {
      float v = sh_ht[(ch * 12 + k) * 34 + o];
      s1 += v; s2 += v * v;
    }
    s1 += __shfl_down(s1, 4);  s2 += __shfl_down(s2, 4);
    s1 += __shfl_down(s1, 2);  s2 += __shfl_down(s2, 2);
    s1 += __shfl_down(s1, 1);  s2 += __shfl_down(s2, 1);
    if (ch == 0) {
      float* slot = stp + (size_t)(blk & 63) * 64;     // hashed partial copy
      atomicAdd(&slot[o], s1);
      atomicAdd(&slot[32 + o], s2);
    }
  }
}

// reduce 64 partial slots -> (scale, shift) for this layer
__global__ void k_bnfinal(const float* __restrict__ stp, const float* __restrict__ g,
                          const float* __restrict__ bb, float* __restrict__ sc) {
  __shared__ float tot[64];
  int t = threadIdx.x;                // 64 threads
  float s = 0.f;
  for (int slot = 0; slot < 64; ++slot) s += stp[slot * 64 + t];
  tot[t] = s;
  __syncthreads();
  if (t < 32) {
    const float N = (float)NPTS;
    float mean = tot[t] / N;
    float var = tot[32 + t] / N - mean * mean;
    float inv = rsqrtf(var + 1e-5f);
    float scale = inv * g[t];
    sc[t] = scale;
    sc[32 + t] = bb[t] - mean * scale;
  }
}

// MLP, LDS-activation + scalar-weight design, 512-thread blocks (8 waves).
// r9 scalar form. Measured: 256thr=492us, 1024thr=593us, 512thr=380us.
// r13: SINGLE launch (9216 blocks) -- the 8-way diagnostic split is obsolete
// (top-5 is now saturated by harness fillBuffer dispatches) and cost ~7
// inter-launch gaps.
__global__ __launch_bounds__(512, 6) void k_mlp(
    const float* __restrict__ h, const float* __restrict__ xin,
    const float* __restrict__ sc,
    const float* __restrict__ w1, const float* __restrict__ b1,
    const float* __restrict__ w2, const float* __restrict__ b2,
    const float* __restrict__ w3, const float* __restrict__ b3,
    const float* __restrict__ w4, const float* __restrict__ b4,
    const float* __restrict__ w5, const float* __restrict__ b5,
    const float* __restrict__ w7, const float* __restrict__ b7,
    float* __restrict__ out) {
  __shared__ float A[64 * 65];    // 16.6 KB (32/64-wide activations)
  __shared__ float Bf[64 * 129];  // 33 KB  (128/32-wide activations)
  __shared__ float P[64 * 9];     // 2.3 KB (fc7 per-wave partials)
  int t = threadIdx.x;
  int p = t & 63;                                      // point within block
  int q = __builtin_amdgcn_readfirstlane(t >> 6);      // wave id 0..7, uniform
  int pt0 = blockIdx.x * 64;

  // phase 0: A[p][c] = leaky(BN3(h)); lanes -> consecutive points (coalesced)
  for (int i = t; i < 64 * 32; i += 512) {
    int c = i >> 6, pp = i & 63;
    int pt = pt0 + pp;
    size_t base = (size_t)(pt / CHS) * C_ * CHS + (pt % CHS);
    float v = h[base + (size_t)c * CHS];
    v = v * sc[c] + sc[32 + c];                        // sc via s_load
    A[pp * 65 + c] = v >= 0.f ? v : 0.1f * v;
  }
  __syncthreads();

  // phase 1: fc1 (32->128): A -> Bf, 16 outputs/thread (m0 = q*16)
  {
    const int m0 = q * 16;
    float acc[16];
    #pragma unroll
    for (int j = 0; j < 16; ++j) acc[j] = b1[m0 + j];
    const float* arow = A + p * 65;
    #pragma unroll 4
    for (int k = 0; k < 32; ++k) {
      float a = arow[k];
      const float* wr = w1 + k * 128 + m0;             // uniform -> s_load
      #pragma unroll
      for (int j = 0; j < 16; ++j) acc[j] += a * wr[j];
    }
    float* brow = Bf + p * 129 + m0;
    #pragma unroll
    for (int j = 0; j < 16; ++j) {
      float v = acc[j];
      brow[j] = v >= 0.f ? v : 0.1f * v;
    }
  }
  __syncthreads();

  // phase 2: fc2 (128->64): Bf -> A, 8 outputs/thread (m0 = q*8)
  {
    const int m0 = q * 8;
    float acc[8];
    #pragma unroll
    for (int j = 0; j < 8; ++j) acc[j] = b2[m0 + j];
    const float* brow = Bf + p * 129;
    #pragma unroll 4
    for (int k = 0; k < 128; ++k) {
      float a = brow[k];
      const float* wr = w2 + k * 64 + m0;              // s_load
      #pragma unroll
      for (int j = 0; j < 8; ++j) acc[j] += a * wr[j];
    }
    float* arow = A + p * 65 + m0;
    #pragma unroll
    for (int j = 0; j < 8; ++j) {
      float v = acc[j];
      arow[j] = v >= 0.f ? v : 0.1f * v;
    }
  }
  __syncthreads();

  // phase 3: fc3 (64->32): A -> Bf (low cols), 4 outputs/thread (m0 = q*4)
  {
    const int m0 = q * 4;
    float acc[4];
    #pragma unroll
    for (int j = 0; j < 4; ++j) acc[j] = b3[m0 + j];
    const float* arow = A + p * 65;
    #pragma unroll 4
    for (int k = 0; k < 64; ++k) {
      float a = arow[k];
      const float* wr = w3 + k * 32 + m0;              // s_load
      #pragma unroll
      for (int j = 0; j < 4; ++j) acc[j] += a * wr[j];
    }
    float* brow = Bf + p * 129 + m0;
    #pragma unroll
    for (int j = 0; j < 4; ++j) {
      float v = acc[j];
      brow[j] = v >= 0.f ? v : 0.1f * v;
    }
  }
  __syncthreads();

  // phase 4: fc4 (32->64): Bf -> A, 8 outputs/thread (m0 = q*8)
  {
    const int m0 = q * 8;
    float acc[8];
    #pragma unroll
    for (int j = 0; j < 8; ++j) acc[j] = b4[m0 + j];
    const float* brow = Bf + p * 129;
    #pragma unroll 4
    for (int k = 0; k < 32; ++k) {
      float a = brow[k];
      const float* wr = w4 + k * 64 + m0;              // s_load
      #pragma unroll
      for (int j = 0; j < 8; ++j) acc[j] += a * wr[j];
    }
    float* arow = A + p * 65 + m0;
    #pragma unroll
    for (int j = 0; j < 8; ++j) {
      float v = acc[j];
      arow[j] = v >= 0.f ? v : 0.1f * v;
    }
  }
  __syncthreads();

  // phase 5: fc5 (64->128) fused with fc7 (128->1): per-wave partial dot
  {
    const int m0 = q * 16;
    float acc[16];
    #pragma unroll
    for (int j = 0; j < 16; ++j) acc[j] = b5[m0 + j];
    const float* arow = A + p * 65;
    #pragma unroll 4
    for (int k = 0; k < 64; ++k) {
      float a = arow[k];
      const float* wr = w5 + k * 128 + m0;             // s_load
      #pragma unroll
      for (int j = 0; j < 16; ++j) acc[j] += a * wr[j];
    }
    float partial = 0.f;
    #pragma unroll
    for (int j = 0; j < 16; ++j) {
      float v = acc[j];
      v = v >= 0.f ? v : 0.1f * v;                     // leaky(fc5)
      partial += v * w7[m0 + j];                       // s_load
    }
    P[p * 9 + q] = partial;
  }
  __syncthreads();

  // phase 6: wave 0 reduces the 8 partials, applies mask, stores
  if (q == 0) {
    int pt = pt0 + p;
    float acc = b7[0];
    #pragma unroll
    for (int j = 0; j < 8; ++j) acc += P[p * 9 + j];
    float T0 = xin[2 * pt + 1];
    float mask = (T0 < 0.01f) ? T0 : 1.0f;
    int z = (pt / NX) % NZ;
    if (z < 2) mask = 0.f;
    out[pt] = acc * mask;
  }
}

__global__ void k_loss(const float* __restrict__ tau, const float* __restrict__ xin,
                       const float* __restrict__ y, float* __restrict__ loss) {
  int pt = blockIdx.x * 256 + threadIdx.x;
  int x = pt % NX, z = (pt / NX) % NZ;
  float tpx = (x < NX - 1) ? tau[pt + 1] : 0.f;
  float tmx = (x > 0) ? tau[pt - 1] : 0.f;
  float tpz = (z < NZ - 1) ? tau[pt + NX] : 0.f;
  float tmz = (z > 0) ? tau[pt - NX] : 0.f;
  float Tpx = (x < NX - 1) ? xin[2 * (pt + 1) + 1] : 0.f;
  float Tmx = (x > 0) ? xin[2 * (pt - 1) + 1] : 0.f;
  float Tpz = (z < NZ - 1) ? xin[2 * (pt + NX) + 1] : 0.f;
  float Tmz = (z > 0) ? xin[2 * (pt - NX) + 1] : 0.f;
  float dx = (tpx - tmx) * 50.f + (Tpx - Tmx) * 50.f;
  float dz = (tpz - tmz) * 50.f + (Tpz - Tmz) * 50.f;
  loss[pt] = dx * dx + dz * dz - y[pt];
}

extern "C" void kernel_launch(void* const* d_in, const int* in_sizes, int n_in,
                              void* d_out, int out_size, void* d_ws, size_t ws_size,
                              hipStream_t stream) {
  (void)in_sizes; (void)n_in; (void)out_size; (void)ws_size;
  const float* xin    = (const float*)d_in[0];
  const float* y      = (const float*)d_in[1];
  const float* fc0_w  = (const float*)d_in[2];
  const float* fc0_b  = (const float*)d_in[3];
  const float* spec_w = (const float*)d_in[4];
  const float* w_w    = (const float*)d_in[5];
  const float* w_b    = (const float*)d_in[6];
  const float* bn_g   = (const float*)d_in[7];
  const float* bn_b   = (const float*)d_in[8];
  const float* fc1_w  = (const float*)d_in[9];
  const float* fc1_b  = (const float*)d_in[10];
  const float* fc2_w  = (const float*)d_in[11];
  const float* fc2_b  = (const float*)d_in[12];
  const float* fc3_w  = (const float*)d_in[13];
  const float* fc3_b  = (const float*)d_in[14];
  const float* fc4_w  = (const float*)d_in[15];
  const float* fc4_b  = (const float*)d_in[16];
  const float* fc5_w  = (const float*)d_in[17];
  const float* fc5_b  = (const float*)d_in[18];
  const float* fc7_w  = (const float*)d_in[19];
  const float* fc7_b  = (const float*)d_in[20];
  float* ws  = (float*)d_ws;
  float* out = (float*)d_out;

  k_init_tw<<<1, 256, 0, stream>>>(ws);
  k_zero_stats<<<64, 256, 0, stream>>>(ws + OFF_STP);
  // NOTE: no k_fc0 -- layer 0 expands fc0 on the fly in k_fwd/k_idftx_fuse.

  float* hsrc = ws + OFF_HA;   // unwritten for l=0; layer-0 kernels don't read it
  float* hdst = ws + OFF_HB;
  for (int l = 0; l < 4; ++l) {
    const float* sc_prev = ws + OFF_SC + (size_t)(l - 1) * 64;  // only read if l>0
    int use_bn = (l > 0) ? 1 : 0;
    float* stp_l = ws + OFF_STP + (size_t)l * 4096;
    k_fwd<<<B_ * C_ * NS, 256, 0, stream>>>(hsrc, xin, fc0_w, fc0_b,
                                            (float2*)(ws + OFF_FZX),
                                            (const float2*)(ws + OFF_TWXF),
                                            (const float2*)(ws + OFF_TWZF), sc_prev, use_bn);
    k_dfts<<<1152, 256, 0, stream>>>((const float2*)(ws + OFF_FZX), (float2*)(ws + OFF_FS),
                                     (const float2*)(ws + OFF_TWSF));
    k_mix<<<576, 256, 0, stream>>>((const float2*)(ws + OFF_FS), spec_w, l,
                                   (float2*)(ws + OFF_G));
    k_idft_sz<<<64 * 32, 256, 0, stream>>>((const float2*)(ws + OFF_G), (float2*)(ws + OFF_FX),
                                           (const float2*)(ws + OFF_TWSI),
                                           (const float2*)(ws + OFF_TWZI));
    k_idftx_fuse<<<B_ * NS * NZ, 256, 0, stream>>>((const float2*)(ws + OFF_FX), hsrc,
                                                   xin, fc0_w, fc0_b,
                                                   w_w + (size_t)l * C_ * C_, w_b + (size_t)l * C_,
                                                   (const float2*)(ws + OFF_TWXI), sc_prev,
                                                   use_bn, hdst, stp_l);
    k_bnfinal<<<1, 64, 0, stream>>>(stp_l, bn_g + (size_t)l * C_,
                                    bn_b + (size_t)l * C_, ws + OFF_SC + (size_t)l * 64);
    float* tmp = hsrc; hsrc = hdst; hdst = tmp;
  }

  // single launch: 64 pts per 512-thread block, 8 output-groups (waves)
  k_mlp<<<NPTS / 64, 512, 0, stream>>>(hsrc, xin, ws + OFF_SC + 192,
                                       fc1_w, fc1_b, fc2_w, fc2_b, fc3_w, fc3_b,
                                       fc4_w, fc4_b, fc5_w, fc5_b, fc7_w, fc7_b, out);
  k_loss<<<NPTS / 256, 256, 0, stream>>>(out, xin, y, out + NPTS);
}